// Round 1
// baseline (1747.869 us; speedup 1.0000x reference)
//
#include <hip/hip_runtime.h>
#include <math.h>

#define NEG_SLOPE 0.2f
#define EPSF 1e-16f

constexpr int FIN = 128;
constexpr int H1  = 4;
constexpr int C   = 64;
constexpr int HC  = 256;   // H1 * C

__device__ inline float wred(float v) {
#pragma unroll
    for (int off = 32; off; off >>= 1) v += __shfl_down(v, off);
    return v;
}

__device__ inline void atomicMaxF(float* addr, float val) {
    if (val >= 0.0f) atomicMax((int*)addr, __float_as_int(val));
    else             atomicMin((unsigned int*)addr, __float_as_uint(val));
}

// fill amax buffers with -inf
__global__ void k_init(float* amax1, float* amax2, int n1, int n2) {
    int i = blockIdx.x * blockDim.x + threadIdx.x;
    if (i < n1) amax1[i] = -INFINITY;
    if (i < n2) amax2[i] = -INFINITY;
}

// sum(edge_attr) -> scal[0]
__global__ void k_ea_sum(const float* __restrict__ ea, int E, float* __restrict__ scal) {
    int i = blockIdx.x * blockDim.x + threadIdx.x;
    float v = (i < E) ? ea[i] : 0.0f;
    v = wred(v);
    __shared__ float sm[4];
    if ((threadIdx.x & 63) == 0) sm[threadIdx.x >> 6] = v;
    __syncthreads();
    if (threadIdx.x == 0) atomicAdd(scal, sm[0] + sm[1] + sm[2] + sm[3]);
}

// scal[1]=ea_mean, scal[2]=we2dot, scal[4..7]=we1dot[h]
__global__ void k_prep(const float* __restrict__ We1, const float* __restrict__ ae1,
                       const float* __restrict__ We2, const float* __restrict__ ae2,
                       float* __restrict__ scal, float inv_E) {
    int t = threadIdx.x;
    float p = We1[t] * ae1[t];
    p = wred(p);
    if ((t & 63) == 0) scal[4 + (t >> 6)] = p;
    if (t < 64) {
        float q = We2[t] * ae2[t];
        q = wred(q);
        if (t == 0) scal[2] = q;
    }
    if (t == 0) scal[1] = scal[0] * inv_E;
}

// h1 = x @ W1 ; a_src1/a_dst1 fused.  one block (256 thr) per node
__global__ void k_gemm1(const float* __restrict__ x, const float* __restrict__ W1,
                        const float* __restrict__ attsrc, const float* __restrict__ attdst,
                        float* __restrict__ h1, float* __restrict__ a_src, float* __restrict__ a_dst) {
    __shared__ float xs[FIN];
    int n = blockIdx.x;
    int t = threadIdx.x;
    if (t < FIN) xs[t] = x[(size_t)n * FIN + t];
    __syncthreads();
    float acc = 0.0f;
#pragma unroll 8
    for (int k = 0; k < FIN; ++k) acc += xs[k] * W1[k * HC + t];
    h1[(size_t)n * HC + t] = acc;
    float ps = wred(acc * attsrc[t]);
    float pd = wred(acc * attdst[t]);
    if ((t & 63) == 0) {
        a_src[n * H1 + (t >> 6)] = ps;
        a_dst[n * H1 + (t >> 6)] = pd;
    }
}

// pass A layer1: alpha raw + segment max
__global__ void k_edgeA1(const int* __restrict__ ei, const float* __restrict__ eattr,
                         const float* __restrict__ scal,
                         const float* __restrict__ a_src, const float* __restrict__ a_dst,
                         float* __restrict__ alpha, float* __restrict__ amax, int E, int Etot) {
    int e = blockIdx.x * blockDim.x + threadIdx.x;
    if (e >= Etot) return;
    int s, d; float ea;
    if (e < E) { s = ei[e]; d = ei[E + e]; ea = eattr[e]; }
    else       { s = e - E; d = s;          ea = scal[1]; }
    const float4 as = *(const float4*)(a_src + (size_t)s * 4);
    const float4 ad = *(const float4*)(a_dst + (size_t)d * 4);
    const float4 we = *(const float4*)(scal + 4);
    float al[4] = { as.x + ad.x + ea * we.x, as.y + ad.y + ea * we.y,
                    as.z + ad.z + ea * we.z, as.w + ad.w + ea * we.w };
#pragma unroll
    for (int h = 0; h < 4; ++h) {
        float v = al[h];
        v = v > 0.0f ? v : NEG_SLOPE * v;
        alpha[(size_t)e * 4 + h] = v;
        atomicMaxF(&amax[d * 4 + h], v);
    }
}

// pass B layer1: exp + denom
__global__ void k_edgeB1(const int* __restrict__ ei, float* __restrict__ alpha,
                         const float* __restrict__ amax, float* __restrict__ denom, int E, int Etot) {
    int e = blockIdx.x * blockDim.x + threadIdx.x;
    if (e >= Etot) return;
    int d = (e < E) ? ei[E + e] : e - E;
#pragma unroll
    for (int h = 0; h < 4; ++h) {
        float ex = expf(alpha[(size_t)e * 4 + h] - amax[d * 4 + h]);
        alpha[(size_t)e * 4 + h] = ex;
        atomicAdd(&denom[d * 4 + h], ex);
    }
}

// pass C layer1: weighted scatter.  one wave per edge, lane covers 4 channels
__global__ void k_edgeC1(const int* __restrict__ ei, const float* __restrict__ alpha,
                         const float* __restrict__ denom, const float* __restrict__ h1,
                         float* __restrict__ out1, int E, int Etot) {
    int wid  = (blockIdx.x * blockDim.x + threadIdx.x) >> 6;
    int lane = threadIdx.x & 63;
    if (wid >= Etot) return;
    int e = wid;
    int s, d;
    if (e < E) { s = ei[e]; d = ei[E + e]; } else { s = d = e - E; }
#pragma unroll
    for (int i = 0; i < 4; ++i) {
        float w = alpha[(size_t)e * 4 + i] / (denom[d * 4 + i] + EPSF);
        int c = i * 64 + lane;
        atomicAdd(&out1[(size_t)d * HC + c], h1[(size_t)s * HC + c] * w);
    }
}

// layer2 gemm: h2 = elu(out1+b1) @ W2 ; a_src2/a_dst2.  4 waves per block, 1 node per wave
__global__ void k_gemm2(const float* __restrict__ out1, const float* __restrict__ b1,
                        const float* __restrict__ W2, const float* __restrict__ attsrc,
                        const float* __restrict__ attdst,
                        float* __restrict__ h2, float* __restrict__ a_src2, float* __restrict__ a_dst2) {
    __shared__ float rows[4][HC];
    int wid = threadIdx.x >> 6, lane = threadIdx.x & 63;
    int n = blockIdx.x * 4 + wid;
#pragma unroll
    for (int i = 0; i < 4; ++i) {
        float v = out1[(size_t)n * HC + lane + i * 64] + b1[lane + i * 64];
        rows[wid][lane + i * 64] = v > 0.0f ? v : expm1f(v);
    }
    __syncthreads();
    float acc = 0.0f;
#pragma unroll 8
    for (int k = 0; k < HC; ++k) acc += rows[wid][k] * W2[k * C + lane];
    h2[(size_t)n * C + lane] = acc;
    float ps = wred(acc * attsrc[lane]);
    float pd = wred(acc * attdst[lane]);
    if (lane == 0) { a_src2[n] = ps; a_dst2[n] = pd; }
}

__global__ void k_edgeA2(const int* __restrict__ ei, const float* __restrict__ eattr,
                         const float* __restrict__ scal,
                         const float* __restrict__ a_src2, const float* __restrict__ a_dst2,
                         float* __restrict__ alpha2, float* __restrict__ amax2, int E, int Etot) {
    int e = blockIdx.x * blockDim.x + threadIdx.x;
    if (e >= Etot) return;
    int s, d; float ea;
    if (e < E) { s = ei[e]; d = ei[E + e]; ea = eattr[e]; }
    else       { s = e - E; d = s;          ea = scal[1]; }
    float al = a_src2[s] + a_dst2[d] + ea * scal[2];
    al = al > 0.0f ? al : NEG_SLOPE * al;
    alpha2[e] = al;
    atomicMaxF(&amax2[d], al);
}

__global__ void k_edgeB2(const int* __restrict__ ei, float* __restrict__ alpha2,
                         const float* __restrict__ amax2, float* __restrict__ denom2, int E, int Etot) {
    int e = blockIdx.x * blockDim.x + threadIdx.x;
    if (e >= Etot) return;
    int d = (e < E) ? ei[E + e] : e - E;
    float ex = expf(alpha2[e] - amax2[d]);
    alpha2[e] = ex;
    atomicAdd(&denom2[d], ex);
}

__global__ void k_edgeC2(const int* __restrict__ ei, const float* __restrict__ alpha2,
                         const float* __restrict__ denom2, const float* __restrict__ h2,
                         float* __restrict__ out2, int E, int Etot) {
    int wid  = (blockIdx.x * blockDim.x + threadIdx.x) >> 6;
    int lane = threadIdx.x & 63;
    if (wid >= Etot) return;
    int e = wid;
    int s, d;
    if (e < E) { s = ei[e]; d = ei[E + e]; } else { s = d = e - E; }
    float w = alpha2[e] / (denom2[d] + EPSF);
    atomicAdd(&out2[(size_t)d * C + lane], h2[(size_t)s * C + lane] * w);
}

// emb = elu(out2+b2); logits = emb@Wfc+bfc; log_softmax.  1 node per wave
__global__ void k_final(const float* __restrict__ out2, const float* __restrict__ b2,
                        const float* __restrict__ Wfc, const float* __restrict__ bfc,
                        float* __restrict__ d_out, int N) {
    int wid = threadIdx.x >> 6, lane = threadIdx.x & 63;
    int n = blockIdx.x * 4 + wid;
    float v = out2[(size_t)n * C + lane] + b2[lane];
    v = v > 0.0f ? v : expm1f(v);
    d_out[(size_t)2 * N + (size_t)n * C + lane] = v;   // emb output
    float p0 = wred(v * Wfc[lane * 2]);
    float p1 = wred(v * Wfc[lane * 2 + 1]);
    if (lane == 0) {
        p0 += bfc[0]; p1 += bfc[1];
        float m = fmaxf(p0, p1);
        float lse = m + logf(expf(p0 - m) + expf(p1 - m));
        d_out[(size_t)n * 2]     = p0 - lse;
        d_out[(size_t)n * 2 + 1] = p1 - lse;
    }
}

extern "C" void kernel_launch(void* const* d_in, const int* in_sizes, int n_in,
                              void* d_out, int out_size, void* d_ws, size_t ws_size,
                              hipStream_t stream) {
    const float* x     = (const float*)d_in[0];
    const int*   ei    = (const int*)  d_in[1];
    const float* eattr = (const float*)d_in[2];
    const float* W1    = (const float*)d_in[3];
    const float* as1   = (const float*)d_in[4];
    const float* ad1   = (const float*)d_in[5];
    const float* We1   = (const float*)d_in[6];
    const float* ae1   = (const float*)d_in[7];
    const float* b1    = (const float*)d_in[8];
    const float* W2    = (const float*)d_in[9];
    const float* as2   = (const float*)d_in[10];
    const float* ad2   = (const float*)d_in[11];
    const float* We2   = (const float*)d_in[12];
    const float* ae2   = (const float*)d_in[13];
    const float* b2    = (const float*)d_in[14];
    const float* Wfc   = (const float*)d_in[15];
    const float* bfc   = (const float*)d_in[16];

    const int N    = in_sizes[0] / FIN;   // 50000
    const int E    = in_sizes[2];         // 800000
    const int Etot = E + N;

    float* w = (float*)d_ws;
    size_t off = 0;
    float* out1   = w + off; off += (size_t)N * HC;
    float* out2   = w + off; off += (size_t)N * C;
    float* denom1 = w + off; off += (size_t)N * H1;
    float* denom2 = w + off; off += (size_t)N;
    off = (off + 3) & ~(size_t)3;
    float* scal   = w + off; off += 8;
    size_t zero_floats = off;
    float* h1     = w + off; off += (size_t)N * HC;
    float* h2     = w + off; off += (size_t)N * C;
    float* a_src1 = w + off; off += (size_t)N * H1;
    float* a_dst1 = w + off; off += (size_t)N * H1;
    float* amax1  = w + off; off += (size_t)N * H1;
    float* a_src2 = w + off; off += (size_t)N;
    float* a_dst2 = w + off; off += (size_t)N;
    float* amax2  = w + off; off += (size_t)N;
    float* alpha1 = w + off; off += (size_t)Etot * H1;
    float* alpha2 = w + off; off += (size_t)Etot;

    hipMemsetAsync(d_ws, 0, zero_floats * sizeof(float), stream);

    {   // amax = -inf
        int n1 = N * H1, n2 = N;
        int g = (n1 + 255) / 256;
        k_init<<<g, 256, 0, stream>>>(amax1, amax2, n1, n2);
    }
    k_ea_sum<<<(E + 255) / 256, 256, 0, stream>>>(eattr, E, scal);
    k_prep<<<1, 256, 0, stream>>>(We1, ae1, We2, ae2, scal, 1.0f / (float)E);

    k_gemm1<<<N, 256, 0, stream>>>(x, W1, as1, ad1, h1, a_src1, a_dst1);

    int ge = (Etot + 255) / 256;
    k_edgeA1<<<ge, 256, 0, stream>>>(ei, eattr, scal, a_src1, a_dst1, alpha1, amax1, E, Etot);
    k_edgeB1<<<ge, 256, 0, stream>>>(ei, alpha1, amax1, denom1, E, Etot);
    int gw = (Etot + 3) / 4;   // 4 waves per 256-thread block
    k_edgeC1<<<gw, 256, 0, stream>>>(ei, alpha1, denom1, h1, out1, E, Etot);

    k_gemm2<<<N / 4, 256, 0, stream>>>(out1, b1, W2, as2, ad2, h2, a_src2, a_dst2);

    k_edgeA2<<<ge, 256, 0, stream>>>(ei, eattr, scal, a_src2, a_dst2, alpha2, amax2, E, Etot);
    k_edgeB2<<<ge, 256, 0, stream>>>(ei, alpha2, amax2, denom2, E, Etot);
    k_edgeC2<<<gw, 256, 0, stream>>>(ei, alpha2, denom2, h2, out2, E, Etot);

    k_final<<<N / 4, 256, 0, stream>>>(out2, b2, Wfc, bfc, (float*)d_out, N);
}

// Round 2
// 821.280 us; speedup vs baseline: 2.1282x; 2.1282x over previous
//
#include <hip/hip_runtime.h>
#include <math.h>

#define NEG_SLOPE 0.2f
#define EPSF 1e-16f

constexpr int FIN = 128;
constexpr int H1  = 4;
constexpr int C   = 64;
constexpr int HC  = 256;   // H1 * C

__device__ inline float wred(float v) {
#pragma unroll
    for (int off = 32; off; off >>= 1) v += __shfl_down(v, off);
    return v;
}

// ---------- tiny prep ----------
// sum(edge_attr) -> scal[0]
__global__ void k_ea_sum(const float* __restrict__ ea, int E, float* __restrict__ scal) {
    int i = blockIdx.x * blockDim.x + threadIdx.x;
    float v = (i < E) ? ea[i] : 0.0f;
    v = wred(v);
    __shared__ float sm[4];
    if ((threadIdx.x & 63) == 0) sm[threadIdx.x >> 6] = v;
    __syncthreads();
    if (threadIdx.x == 0) atomicAdd(scal, sm[0] + sm[1] + sm[2] + sm[3]);
}

// scal[1]=ea_mean, scal[2]=we2dot, scal[4..7]=we1dot[h]
__global__ void k_prep(const float* __restrict__ We1, const float* __restrict__ ae1,
                       const float* __restrict__ We2, const float* __restrict__ ae2,
                       float* __restrict__ scal, float inv_E) {
    int t = threadIdx.x;
    float p = We1[t] * ae1[t];
    p = wred(p);
    if ((t & 63) == 0) scal[4 + (t >> 6)] = p;
    if (t < 64) {
        float q = We2[t] * ae2[t];
        q = wred(q);
        if (t == 0) scal[2] = q;
    }
    if (t == 0) scal[1] = scal[0] * inv_E;
}

// ---------- CSR build (edges grouped by dst; same CSR reused by both layers) ----------
__global__ void k_hist(const int* __restrict__ ei, int* __restrict__ deg, int E, int Etot) {
    int e = blockIdx.x * blockDim.x + threadIdx.x;
    if (e >= Etot) return;
    int d = (e < E) ? ei[E + e] : e - E;
    atomicAdd(&deg[d], 1);
}

__global__ void k_scan1(const int* __restrict__ deg, int* __restrict__ rowstart,
                        int* __restrict__ bsums, int N) {
    __shared__ int sm[256];
    int i = blockIdx.x * 256 + threadIdx.x;
    int v = (i < N) ? deg[i] : 0;
    sm[threadIdx.x] = v;
    __syncthreads();
    for (int off = 1; off < 256; off <<= 1) {
        int t = (threadIdx.x >= off) ? sm[threadIdx.x - off] : 0;
        __syncthreads();
        sm[threadIdx.x] += t;
        __syncthreads();
    }
    if (i < N) rowstart[i] = sm[threadIdx.x] - v;   // exclusive
    if (threadIdx.x == 255) bsums[blockIdx.x] = sm[255];
}

// nb <= 256 (N=50000 -> 196 blocks)
__global__ void k_scan2(int* __restrict__ bsums, int nb) {
    __shared__ int sm[256];
    int v = (threadIdx.x < nb) ? bsums[threadIdx.x] : 0;
    sm[threadIdx.x] = v;
    __syncthreads();
    for (int off = 1; off < 256; off <<= 1) {
        int t = (threadIdx.x >= off) ? sm[threadIdx.x - off] : 0;
        __syncthreads();
        sm[threadIdx.x] += t;
        __syncthreads();
    }
    if (threadIdx.x < nb) bsums[threadIdx.x] = sm[threadIdx.x] - v;   // exclusive
}

__global__ void k_scan3(int* __restrict__ rowstart, const int* __restrict__ bsums, int N) {
    int i = blockIdx.x * 256 + threadIdx.x;
    if (i < N) rowstart[i] += bsums[blockIdx.x];
}

__global__ void k_scatter(const int* __restrict__ ei, const float* __restrict__ eattr,
                          const float* __restrict__ scal, const int* __restrict__ rowstart,
                          int* __restrict__ cursor, int* __restrict__ csr_s,
                          float* __restrict__ csr_ea, int E, int Etot) {
    int e = blockIdx.x * blockDim.x + threadIdx.x;
    if (e >= Etot) return;
    int s, d; float ea;
    if (e < E) { s = ei[e]; d = ei[E + e]; ea = eattr[e]; }
    else       { s = e - E; d = s;          ea = scal[1]; }
    int pos = atomicAdd(&cursor[d], 1);
    int idx = rowstart[d] + pos;
    csr_s[idx] = s;
    csr_ea[idx] = ea;
}

// ---------- layer 1 GEMM: h1 = x @ W1, fused a_src1/a_dst1.  8 nodes per block ----------
__global__ void k_gemm1(const float* __restrict__ x, const float* __restrict__ W1,
                        const float* __restrict__ attsrc, const float* __restrict__ attdst,
                        float* __restrict__ h1, float* __restrict__ a_src, float* __restrict__ a_dst) {
    __shared__ float xs[8][FIN];
    int n0 = blockIdx.x * 8;
    int t = threadIdx.x;
#pragma unroll
    for (int i = 0; i < 4; ++i) {
        int idx = t + i * 256;
        ((float*)xs)[idx] = x[(size_t)n0 * FIN + idx];
    }
    __syncthreads();
    float acc[8] = {0, 0, 0, 0, 0, 0, 0, 0};
    for (int k = 0; k < FIN; ++k) {
        float wv = W1[k * HC + t];
#pragma unroll
        for (int i = 0; i < 8; ++i) acc[i] += xs[i][k] * wv;
    }
    int g = t >> 6;           // head index (wave id)
    float asr = attsrc[t], adr = attdst[t];
#pragma unroll
    for (int i = 0; i < 8; ++i) {
        h1[(size_t)(n0 + i) * HC + t] = acc[i];
        float ps = wred(acc[i] * asr);
        float pd = wred(acc[i] * adr);
        if ((t & 63) == 0) {
            a_src[(n0 + i) * H1 + g] = ps;
            a_dst[(n0 + i) * H1 + g] = pd;
        }
    }
}

// ---------- layer 1 aggregation: per-dst softmax + weighted gather, fused bias+ELU ----------
// one block (256 thr) per node; thread t = channel, head h = t>>6
__global__ void k_agg1(const int* __restrict__ rowstart, const int* __restrict__ deg,
                       const int* __restrict__ csr_s, const float* __restrict__ csr_ea,
                       const float* __restrict__ a_src, const float* __restrict__ a_dst,
                       const float* __restrict__ scal, const float* __restrict__ h1,
                       const float* __restrict__ b1, float* __restrict__ out1) {
    int n = blockIdx.x;
    int t = threadIdx.x;
    int h = t >> 6;
    int rs = rowstart[n], cnt = deg[n];
    float adh = a_dst[n * H1 + h];
    float wh  = scal[4 + h];
    // pass 1: segment max (per head; redundant across the 64 lanes of a wave)
    float m = -INFINITY;
    for (int j = 0; j < cnt; ++j) {
        int s = csr_s[rs + j];
        float al = a_src[s * H1 + h] + adh + csr_ea[rs + j] * wh;
        al = al > 0.0f ? al : NEG_SLOPE * al;
        m = fmaxf(m, al);
    }
    // pass 2: exp, denom, weighted gather
    float den = 0.0f, acc = 0.0f;
    for (int j = 0; j < cnt; ++j) {
        int s = csr_s[rs + j];
        float al = a_src[s * H1 + h] + adh + csr_ea[rs + j] * wh;
        al = al > 0.0f ? al : NEG_SLOPE * al;
        float w = expf(al - m);
        den += w;
        acc += h1[(size_t)s * HC + t] * w;
    }
    float v = acc / (den + EPSF) + b1[t];
    out1[(size_t)n * HC + t] = v > 0.0f ? v : expm1f(v);   // ELU fused
}

// ---------- layer 2 GEMM: h2 = out1 @ W2, fused a_src2/a_dst2.  8 nodes per block ----------
__global__ void k_gemm2(const float* __restrict__ out1, const float* __restrict__ W2,
                        const float* __restrict__ attsrc, const float* __restrict__ attdst,
                        float* __restrict__ h2, float* __restrict__ a_src2, float* __restrict__ a_dst2) {
    __shared__ float rows[8][HC];
    int n0 = blockIdx.x * 8;
    int t = threadIdx.x;
#pragma unroll
    for (int i = 0; i < 8; ++i) {
        int idx = t + i * 256;
        ((float*)rows)[idx] = out1[(size_t)n0 * HC + idx];
    }
    __syncthreads();
    int c = t & 63, g = t >> 6;      // wave g handles nodes g and g+4
    float acc0 = 0.0f, acc1 = 0.0f;
    for (int k = 0; k < HC; ++k) {
        float wv = W2[k * C + c];
        acc0 += rows[g][k] * wv;
        acc1 += rows[g + 4][k] * wv;
    }
    float asr = attsrc[c], adr = attdst[c];
    h2[(size_t)(n0 + g) * C + c]     = acc0;
    h2[(size_t)(n0 + g + 4) * C + c] = acc1;
    float ps0 = wred(acc0 * asr), pd0 = wred(acc0 * adr);
    float ps1 = wred(acc1 * asr), pd1 = wred(acc1 * adr);
    if (c == 0) {
        a_src2[n0 + g] = ps0;     a_dst2[n0 + g] = pd0;
        a_src2[n0 + g + 4] = ps1; a_dst2[n0 + g + 4] = pd1;
    }
}

// ---------- layer 2 aggregation + classifier head, fully fused ----------
// one wave per node (4 nodes per 256-thread block); lane = channel
__global__ void k_agg2(const int* __restrict__ rowstart, const int* __restrict__ deg,
                       const int* __restrict__ csr_s, const float* __restrict__ csr_ea,
                       const float* __restrict__ a_src2, const float* __restrict__ a_dst2,
                       const float* __restrict__ scal, const float* __restrict__ h2,
                       const float* __restrict__ b2, const float* __restrict__ Wfc,
                       const float* __restrict__ bfc, float* __restrict__ d_out, int N) {
    int wid = threadIdx.x >> 6, lane = threadIdx.x & 63;
    int n = blockIdx.x * 4 + wid;
    int rs = rowstart[n], cnt = deg[n];
    float adv = a_dst2[n];
    float w2  = scal[2];
    float m = -INFINITY;
    for (int j = 0; j < cnt; ++j) {
        float al = a_src2[csr_s[rs + j]] + adv + csr_ea[rs + j] * w2;
        al = al > 0.0f ? al : NEG_SLOPE * al;
        m = fmaxf(m, al);
    }
    float den = 0.0f, acc = 0.0f;
    for (int j = 0; j < cnt; ++j) {
        int s = csr_s[rs + j];
        float al = a_src2[s] + adv + csr_ea[rs + j] * w2;
        al = al > 0.0f ? al : NEG_SLOPE * al;
        float w = expf(al - m);
        den += w;
        acc += h2[(size_t)s * C + lane] * w;
    }
    float v = acc / (den + EPSF) + b2[lane];
    v = v > 0.0f ? v : expm1f(v);                          // ELU -> emb
    d_out[(size_t)2 * N + (size_t)n * C + lane] = v;       // output 1
    float p0 = wred(v * Wfc[lane * 2]);
    float p1 = wred(v * Wfc[lane * 2 + 1]);
    if (lane == 0) {
        p0 += bfc[0]; p1 += bfc[1];
        float mm = fmaxf(p0, p1);
        float lse = mm + logf(expf(p0 - mm) + expf(p1 - mm));
        d_out[(size_t)n * 2]     = p0 - lse;               // output 0
        d_out[(size_t)n * 2 + 1] = p1 - lse;
    }
}

extern "C" void kernel_launch(void* const* d_in, const int* in_sizes, int n_in,
                              void* d_out, int out_size, void* d_ws, size_t ws_size,
                              hipStream_t stream) {
    const float* x     = (const float*)d_in[0];
    const int*   ei    = (const int*)  d_in[1];
    const float* eattr = (const float*)d_in[2];
    const float* W1    = (const float*)d_in[3];
    const float* as1   = (const float*)d_in[4];
    const float* ad1   = (const float*)d_in[5];
    const float* We1   = (const float*)d_in[6];
    const float* ae1   = (const float*)d_in[7];
    const float* b1    = (const float*)d_in[8];
    const float* W2    = (const float*)d_in[9];
    const float* as2   = (const float*)d_in[10];
    const float* ad2   = (const float*)d_in[11];
    const float* We2   = (const float*)d_in[12];
    const float* ae2   = (const float*)d_in[13];
    const float* b2    = (const float*)d_in[14];
    const float* Wfc   = (const float*)d_in[15];
    const float* bfc   = (const float*)d_in[16];

    const int N    = in_sizes[0] / FIN;   // 50000
    const int E    = in_sizes[2];         // 800000
    const int Etot = E + N;

    char* wsb = (char*)d_ws;
    size_t off = 0;
    auto alloc = [&](size_t elems) { void* p = wsb + off; off += elems * 4; return p; };

    // ---- zero-initialized region (front) ----
    int*   deg    = (int*)  alloc(N);
    int*   cursor = (int*)  alloc(N);
    float* scal   = (float*)alloc(8);
    size_t zero_bytes = off;
    // ---- rest ----
    int*   rowstart = (int*)  alloc(N);
    int*   bsums    = (int*)  alloc(256);
    int*   csr_s    = (int*)  alloc(Etot);
    float* csr_ea   = (float*)alloc(Etot);
    float* h1       = (float*)alloc((size_t)N * HC);
    float* out1     = (float*)alloc((size_t)N * HC);
    float* h2       = (float*)alloc((size_t)N * C);
    float* a_src1   = (float*)alloc((size_t)N * H1);
    float* a_dst1   = (float*)alloc((size_t)N * H1);
    float* a_src2   = (float*)alloc(N);
    float* a_dst2   = (float*)alloc(N);

    hipMemsetAsync(d_ws, 0, zero_bytes, stream);

    k_ea_sum<<<(E + 255) / 256, 256, 0, stream>>>(eattr, E, scal);
    k_prep<<<1, 256, 0, stream>>>(We1, ae1, We2, ae2, scal, 1.0f / (float)E);

    int ge = (Etot + 255) / 256;
    int nb = (N + 255) / 256;
    k_hist<<<ge, 256, 0, stream>>>(ei, deg, E, Etot);
    k_scan1<<<nb, 256, 0, stream>>>(deg, rowstart, bsums, N);
    k_scan2<<<1, 256, 0, stream>>>(bsums, nb);
    k_scan3<<<nb, 256, 0, stream>>>(rowstart, bsums, N);
    k_scatter<<<ge, 256, 0, stream>>>(ei, eattr, scal, rowstart, cursor, csr_s, csr_ea, E, Etot);

    k_gemm1<<<N / 8, 256, 0, stream>>>(x, W1, as1, ad1, h1, a_src1, a_dst1);
    k_agg1<<<N, 256, 0, stream>>>(rowstart, deg, csr_s, csr_ea, a_src1, a_dst1, scal, h1, b1, out1);
    k_gemm2<<<N / 8, 256, 0, stream>>>(out1, W2, as2, ad2, h2, a_src2, a_dst2);
    k_agg2<<<N / 4, 256, 0, stream>>>(rowstart, deg, csr_s, csr_ea, a_src2, a_dst2, scal, h2,
                                      b2, Wfc, bfc, (float*)d_out, N);
}

// Round 4
// 642.953 us; speedup vs baseline: 2.7185x; 1.2774x over previous
//
#include <hip/hip_runtime.h>
#include <math.h>

#define NEG_SLOPE 0.2f
#define EPSF 1e-16f

constexpr int FIN = 128;
constexpr int H1  = 4;
constexpr int C   = 64;
constexpr int HC  = 256;   // H1 * C

__device__ inline float wredsum(float v) {
#pragma unroll
    for (int off = 32; off; off >>= 1) v += __shfl_down(v, off);
    return v;
}
__device__ inline float wredmax(float v) {
#pragma unroll
    for (int off = 32; off; off >>= 1) v = fmaxf(v, __shfl_down(v, off));
    return v;
}

// ---------- tiny prep ----------
__global__ void k_ea_sum(const float* __restrict__ ea, int E, float* __restrict__ scal) {
    int i = blockIdx.x * blockDim.x + threadIdx.x;
    float v = (i < E) ? ea[i] : 0.0f;
    v = wredsum(v);
    __shared__ float sm[4];
    if ((threadIdx.x & 63) == 0) sm[threadIdx.x >> 6] = v;
    __syncthreads();
    if (threadIdx.x == 0) atomicAdd(scal, sm[0] + sm[1] + sm[2] + sm[3]);
}

// scal[1]=ea_mean, scal[2]=we2dot, scal[4..7]=we1dot[h]
__global__ void k_prep(const float* __restrict__ We1, const float* __restrict__ ae1,
                       const float* __restrict__ We2, const float* __restrict__ ae2,
                       float* __restrict__ scal, float inv_E) {
    int t = threadIdx.x;
    float p = We1[t] * ae1[t];
    p = wredsum(p);
    if ((t & 63) == 0) scal[4 + (t >> 6)] = p;
    if (t < 64) {
        float q = We2[t] * ae2[t];
        q = wredsum(q);
        if (t == 0) scal[2] = q;
    }
    if (t == 0) scal[1] = scal[0] * inv_E;
}

// ---------- CSR build (edges grouped by dst) ----------
__global__ void k_hist(const int* __restrict__ ei, int* __restrict__ deg, int E, int Etot) {
    int e = blockIdx.x * blockDim.x + threadIdx.x;
    if (e >= Etot) return;
    int d = (e < E) ? ei[E + e] : e - E;
    atomicAdd(&deg[d], 1);
}

__global__ void k_scan1(const int* __restrict__ deg, int* __restrict__ rowstart,
                        int* __restrict__ bsums, int N) {
    __shared__ int sm[256];
    int i = blockIdx.x * 256 + threadIdx.x;
    int v = (i < N) ? deg[i] : 0;
    sm[threadIdx.x] = v;
    __syncthreads();
    for (int off = 1; off < 256; off <<= 1) {
        int t = (threadIdx.x >= off) ? sm[threadIdx.x - off] : 0;
        __syncthreads();
        sm[threadIdx.x] += t;
        __syncthreads();
    }
    if (i < N) rowstart[i] = sm[threadIdx.x] - v;   // exclusive
    if (threadIdx.x == 255) bsums[blockIdx.x] = sm[255];
}

__global__ void k_scan2(int* __restrict__ bsums, int nb) {
    __shared__ int sm[256];
    int v = (threadIdx.x < nb) ? bsums[threadIdx.x] : 0;
    sm[threadIdx.x] = v;
    __syncthreads();
    for (int off = 1; off < 256; off <<= 1) {
        int t = (threadIdx.x >= off) ? sm[threadIdx.x - off] : 0;
        __syncthreads();
        sm[threadIdx.x] += t;
        __syncthreads();
    }
    if (threadIdx.x < nb) bsums[threadIdx.x] = sm[threadIdx.x] - v;   // exclusive
}

__global__ void k_scan3(int* __restrict__ rowstart, const int* __restrict__ bsums, int N) {
    int i = blockIdx.x * 256 + threadIdx.x;
    if (i < N) rowstart[i] += bsums[blockIdx.x];
}

__global__ void k_scatter(const int* __restrict__ ei, const float* __restrict__ eattr,
                          const float* __restrict__ scal, const int* __restrict__ rowstart,
                          int* __restrict__ cursor, int2* __restrict__ csr, int E, int Etot) {
    int e = blockIdx.x * blockDim.x + threadIdx.x;
    if (e >= Etot) return;
    int s, d; float ea;
    if (e < E) { s = ei[e]; d = ei[E + e]; ea = eattr[e]; }
    else       { s = e - E; d = s;          ea = scal[1]; }
    int pos = atomicAdd(&cursor[d], 1);
    csr[rowstart[d] + pos] = make_int2(s, __float_as_int(ea));
}

// ---------- layer 1 GEMM: h1 = x @ W1, fused a_src1/a_dst1.  16 nodes per block ----------
__global__ void k_gemm1(const float* __restrict__ x, const float* __restrict__ W1,
                        const float* __restrict__ attsrc, const float* __restrict__ attdst,
                        float* __restrict__ h1, float* __restrict__ a_src, float* __restrict__ a_dst) {
    __shared__ float xs[16][FIN];   // 8 KB
    int n0 = blockIdx.x * 16;
    int t = threadIdx.x;
#pragma unroll
    for (int i = 0; i < 8; ++i) {
        int idx = t + i * 256;
        ((float*)xs)[idx] = x[(size_t)n0 * FIN + idx];
    }
    __syncthreads();
    float acc[16];
#pragma unroll
    for (int i = 0; i < 16; ++i) acc[i] = 0.0f;
#pragma unroll 4
    for (int k = 0; k < FIN; ++k) {
        float wv = W1[k * HC + t];
#pragma unroll
        for (int i = 0; i < 16; ++i) acc[i] += xs[i][k] * wv;
    }
    int g = t >> 6;   // head (wave id)
    float asr = attsrc[t], adr = attdst[t];
#pragma unroll
    for (int i = 0; i < 16; ++i) {
        h1[(size_t)(n0 + i) * HC + t] = acc[i];
        float ps = wredsum(acc[i] * asr);
        float pd = wredsum(acc[i] * adr);
        if ((t & 63) == 0) {
            a_src[(n0 + i) * H1 + g] = ps;
            a_dst[(n0 + i) * H1 + g] = pd;
        }
    }
}

// ---------- layer 1 aggregation: lane-parallel online softmax + shuffle-broadcast gather ----------
// one block per node; wave = head; lane = channel within head
__global__ void k_agg1(const int* __restrict__ rowstart, const int* __restrict__ deg,
                       const int2* __restrict__ csr,
                       const float* __restrict__ a_src, const float* __restrict__ a_dst,
                       const float* __restrict__ scal, const float* __restrict__ h1,
                       const float* __restrict__ b1, float* __restrict__ out1) {
    int n = blockIdx.x;
    int h = threadIdx.x >> 6, lane = threadIdx.x & 63;
    int rs = rowstart[n], cnt = deg[n];
    float adh = a_dst[n * H1 + h];
    float wh  = scal[4 + h];
    const float* hrow = h1 + h * 64 + lane;
    float M = -INFINITY, den = 0.0f, acc = 0.0f;
    for (int base = 0; base < cnt; base += 64) {
        int j = base + lane;
        int sj = 0; float al = -INFINITY;
        if (j < cnt) {
            int2 cv = csr[rs + j];
            sj = cv.x;
            al = a_src[sj * H1 + h] + adh + __int_as_float(cv.y) * wh;
            al = al > 0.0f ? al : NEG_SLOPE * al;
        }
        float cm = wredmax(al); cm = __shfl(cm, 0);
        float newM = fmaxf(M, cm);
        float sc = __expf(M - newM);    // first chunk: exp(-inf)=0 zeroes den/acc
        den *= sc; acc *= sc; M = newM;
        float w = __expf(al - M);       // invalid lanes: exp(-inf)=0
        den += w;
        int m = min(64, cnt - base);
#pragma unroll 4
        for (int jj = 0; jj < m; ++jj) {
            int   s  = __shfl(sj, jj);
            float ww = __shfl(w, jj);
            acc += hrow[(size_t)s * HC] * ww;
        }
    }
    float dt = wredsum(den); dt = __shfl(dt, 0);
    int t = threadIdx.x;
    float v = acc / (dt + EPSF) + b1[t];
    out1[(size_t)n * HC + t] = v > 0.0f ? v : expm1f(v);   // ELU fused
}

// ---------- layer 2 GEMM: h2 = out1 @ W2, fused a_src2/a_dst2.  16 nodes per block ----------
__global__ void k_gemm2(const float* __restrict__ out1, const float* __restrict__ W2,
                        const float* __restrict__ attsrc, const float* __restrict__ attdst,
                        float* __restrict__ h2, float* __restrict__ a_src2, float* __restrict__ a_dst2) {
    __shared__ float rows[16][HC];   // 16 KB
    int n0 = blockIdx.x * 16;
    int t = threadIdx.x;
#pragma unroll
    for (int i = 0; i < 16; ++i) {
        int idx = t + i * 256;
        ((float*)rows)[idx] = out1[(size_t)n0 * HC + idx];
    }
    __syncthreads();
    int c = t & 63, g = t >> 6;   // wave g handles nodes g, g+4, g+8, g+12
    float acc[4] = {0, 0, 0, 0};
#pragma unroll 4
    for (int k = 0; k < HC; ++k) {
        float wv = W2[k * C + c];
#pragma unroll
        for (int q = 0; q < 4; ++q) acc[q] += rows[g + 4 * q][k] * wv;
    }
    float asr = attsrc[c], adr = attdst[c];
#pragma unroll
    for (int q = 0; q < 4; ++q) {
        int n = n0 + g + 4 * q;
        h2[(size_t)n * C + c] = acc[q];
        float ps = wredsum(acc[q] * asr);
        float pd = wredsum(acc[q] * adr);
        if (c == 0) { a_src2[n] = ps; a_dst2[n] = pd; }
    }
}

// ---------- layer 2 aggregation + classifier head ----------
// one wave per node (4 per block); lane = channel
__global__ void k_agg2(const int* __restrict__ rowstart, const int* __restrict__ deg,
                       const int2* __restrict__ csr,
                       const float* __restrict__ a_src2, const float* __restrict__ a_dst2,
                       const float* __restrict__ scal, const float* __restrict__ h2,
                       const float* __restrict__ b2, const float* __restrict__ Wfc,
                       const float* __restrict__ bfc, float* __restrict__ d_out, int N) {
    int wid = threadIdx.x >> 6, lane = threadIdx.x & 63;
    int n = blockIdx.x * 4 + wid;
    int rs = rowstart[n], cnt = deg[n];
    float adv = a_dst2[n];
    float w2  = scal[2];
    float M = -INFINITY, den = 0.0f, acc = 0.0f;
    for (int base = 0; base < cnt; base += 64) {
        int j = base + lane;
        int sj = 0; float al = -INFINITY;
        if (j < cnt) {
            int2 cv = csr[rs + j];
            sj = cv.x;
            al = a_src2[sj] + adv + __int_as_float(cv.y) * w2;
            al = al > 0.0f ? al : NEG_SLOPE * al;
        }
        float cm = wredmax(al); cm = __shfl(cm, 0);
        float newM = fmaxf(M, cm);
        float sc = __expf(M - newM);
        den *= sc; acc *= sc; M = newM;
        float w = __expf(al - M);
        den += w;
        int m = min(64, cnt - base);
#pragma unroll 4
        for (int jj = 0; jj < m; ++jj) {
            int   s  = __shfl(sj, jj);
            float ww = __shfl(w, jj);
            acc += h2[(size_t)s * C + lane] * ww;
        }
    }
    float dt = wredsum(den); dt = __shfl(dt, 0);
    float v = acc / (dt + EPSF) + b2[lane];
    v = v > 0.0f ? v : expm1f(v);                          // ELU -> emb
    d_out[(size_t)2 * N + (size_t)n * C + lane] = v;       // output 1
    float p0 = wredsum(v * Wfc[lane * 2]);
    float p1 = wredsum(v * Wfc[lane * 2 + 1]);
    if (lane == 0) {
        p0 += bfc[0]; p1 += bfc[1];
        float mm = fmaxf(p0, p1);
        float lse = mm + logf(__expf(p0 - mm) + __expf(p1 - mm));
        d_out[(size_t)n * 2]     = p0 - lse;               // output 0
        d_out[(size_t)n * 2 + 1] = p1 - lse;
    }
}

extern "C" void kernel_launch(void* const* d_in, const int* in_sizes, int n_in,
                              void* d_out, int out_size, void* d_ws, size_t ws_size,
                              hipStream_t stream) {
    const float* x     = (const float*)d_in[0];
    const int*   ei    = (const int*)  d_in[1];
    const float* eattr = (const float*)d_in[2];
    const float* W1    = (const float*)d_in[3];
    const float* as1   = (const float*)d_in[4];
    const float* ad1   = (const float*)d_in[5];
    const float* We1   = (const float*)d_in[6];
    const float* ae1   = (const float*)d_in[7];
    const float* b1    = (const float*)d_in[8];
    const float* W2    = (const float*)d_in[9];
    const float* as2   = (const float*)d_in[10];
    const float* ad2   = (const float*)d_in[11];
    const float* We2   = (const float*)d_in[12];
    const float* ae2   = (const float*)d_in[13];
    const float* b2    = (const float*)d_in[14];
    const float* Wfc   = (const float*)d_in[15];
    const float* bfc   = (const float*)d_in[16];

    const int N    = in_sizes[0] / FIN;   // 50000
    const int E    = in_sizes[2];         // 800000
    const int Etot = E + N;

    char* wsb = (char*)d_ws;
    size_t off = 0;
    auto alloc = [&](size_t elems) {
        off = (off + 7) & ~(size_t)7;     // 8B align every buffer
        void* p = wsb + off; off += elems * 4; return p;
    };

    // ---- zero-initialized region (front) ----
    int*   deg    = (int*)  alloc(N);
    int*   cursor = (int*)  alloc(N);
    float* scal   = (float*)alloc(8);
    size_t zero_bytes = (off + 7) & ~(size_t)7;
    // ---- rest ----
    int*   rowstart = (int*)  alloc(N);
    int*   bsums    = (int*)  alloc(256);
    int2*  csr      = (int2*) alloc((size_t)Etot * 2);
    float* h1       = (float*)alloc((size_t)N * HC);
    float* out1     = (float*)alloc((size_t)N * HC);
    float* h2       = (float*)alloc((size_t)N * C);
    float* a_src1   = (float*)alloc((size_t)N * H1);
    float* a_dst1   = (float*)alloc((size_t)N * H1);
    float* a_src2   = (float*)alloc(N);
    float* a_dst2   = (float*)alloc(N);

    hipMemsetAsync(d_ws, 0, zero_bytes, stream);

    k_ea_sum<<<(E + 255) / 256, 256, 0, stream>>>(eattr, E, scal);
    k_prep<<<1, 256, 0, stream>>>(We1, ae1, We2, ae2, scal, 1.0f / (float)E);

    int ge = (Etot + 255) / 256;
    int nb = (N + 255) / 256;
    k_hist<<<ge, 256, 0, stream>>>(ei, deg, E, Etot);
    k_scan1<<<nb, 256, 0, stream>>>(deg, rowstart, bsums, N);
    k_scan2<<<1, 256, 0, stream>>>(bsums, nb);
    k_scan3<<<nb, 256, 0, stream>>>(rowstart, bsums, N);
    k_scatter<<<ge, 256, 0, stream>>>(ei, eattr, scal, rowstart, cursor, csr, E, Etot);

    k_gemm1<<<N / 16, 256, 0, stream>>>(x, W1, as1, ad1, h1, a_src1, a_dst1);
    k_agg1<<<N, 256, 0, stream>>>(rowstart, deg, csr, a_src1, a_dst1, scal, h1, b1, out1);
    k_gemm2<<<N / 16, 256, 0, stream>>>(out1, W2, as2, ad2, h2, a_src2, a_dst2);
    k_agg2<<<N / 4, 256, 0, stream>>>(rowstart, deg, csr, a_src2, a_dst2, scal, h2,
                                      b2, Wfc, bfc, (float*)d_out, N);
}

// Round 5
// 549.344 us; speedup vs baseline: 3.1817x; 1.1704x over previous
//
#include <hip/hip_runtime.h>
#include <math.h>

#define NEG_SLOPE 0.2f
#define EPSF 1e-16f

constexpr int FIN = 128;
constexpr int H1  = 4;
constexpr int C   = 64;
constexpr int HC  = 256;   // H1 * C

__device__ inline float wredsum(float v) {
#pragma unroll
    for (int off = 32; off; off >>= 1) v += __shfl_down(v, off);
    return v;
}
__device__ inline float wredmax(float v) {
#pragma unroll
    for (int off = 32; off; off >>= 1) v = fmaxf(v, __shfl_down(v, off));
    return v;
}
__device__ inline float4 wredmax4(float4 v) {
#pragma unroll
    for (int off = 32; off; off >>= 1) {
        v.x = fmaxf(v.x, __shfl_down(v.x, off));
        v.y = fmaxf(v.y, __shfl_down(v.y, off));
        v.z = fmaxf(v.z, __shfl_down(v.z, off));
        v.w = fmaxf(v.w, __shfl_down(v.w, off));
    }
    return v;
}
__device__ inline float4 wredsum4(float4 v) {
#pragma unroll
    for (int off = 32; off; off >>= 1) {
        v.x += __shfl_down(v.x, off);
        v.y += __shfl_down(v.y, off);
        v.z += __shfl_down(v.z, off);
        v.w += __shfl_down(v.w, off);
    }
    return v;
}
__device__ inline float4 bcast4(float4 v) {
    v.x = __shfl(v.x, 0); v.y = __shfl(v.y, 0);
    v.z = __shfl(v.z, 0); v.w = __shfl(v.w, 0);
    return v;
}
__device__ inline float comp4(float4 v, int i) {
    return i == 0 ? v.x : (i == 1 ? v.y : (i == 2 ? v.z : v.w));
}

// ---------- tiny prep ----------
__global__ void k_ea_sum(const float* __restrict__ ea, int E, float* __restrict__ scal) {
    int i = blockIdx.x * blockDim.x + threadIdx.x;
    float v = (i < E) ? ea[i] : 0.0f;
    v = wredsum(v);
    __shared__ float sm[4];
    if ((threadIdx.x & 63) == 0) sm[threadIdx.x >> 6] = v;
    __syncthreads();
    if (threadIdx.x == 0) atomicAdd(scal, sm[0] + sm[1] + sm[2] + sm[3]);
}

// scal[1]=ea_mean, scal[2]=we2dot, scal[4..7]=we1dot[h]
__global__ void k_prep(const float* __restrict__ We1, const float* __restrict__ ae1,
                       const float* __restrict__ We2, const float* __restrict__ ae2,
                       float* __restrict__ scal, float inv_E) {
    int t = threadIdx.x;
    float p = We1[t] * ae1[t];
    p = wredsum(p);
    if ((t & 63) == 0) scal[4 + (t >> 6)] = p;
    if (t < 64) {
        float q = We2[t] * ae2[t];
        q = wredsum(q);
        if (t == 0) scal[2] = q;
    }
    if (t == 0) scal[1] = scal[0] * inv_E;
}

// ---------- CSR build (edges grouped by dst) ----------
__global__ void k_hist(const int* __restrict__ ei, int* __restrict__ deg, int E, int Etot) {
    int e = blockIdx.x * blockDim.x + threadIdx.x;
    if (e >= Etot) return;
    int d = (e < E) ? ei[E + e] : e - E;
    atomicAdd(&deg[d], 1);
}

__global__ void k_scan1(const int* __restrict__ deg, int* __restrict__ rowstart,
                        int* __restrict__ bsums, int N) {
    __shared__ int sm[256];
    int i = blockIdx.x * 256 + threadIdx.x;
    int v = (i < N) ? deg[i] : 0;
    sm[threadIdx.x] = v;
    __syncthreads();
    for (int off = 1; off < 256; off <<= 1) {
        int t = (threadIdx.x >= off) ? sm[threadIdx.x - off] : 0;
        __syncthreads();
        sm[threadIdx.x] += t;
        __syncthreads();
    }
    if (i < N) rowstart[i] = sm[threadIdx.x] - v;   // exclusive
    if (threadIdx.x == 255) bsums[blockIdx.x] = sm[255];
}

__global__ void k_scan2(int* __restrict__ bsums, int nb) {
    __shared__ int sm[256];
    int v = (threadIdx.x < nb) ? bsums[threadIdx.x] : 0;
    sm[threadIdx.x] = v;
    __syncthreads();
    for (int off = 1; off < 256; off <<= 1) {
        int t = (threadIdx.x >= off) ? sm[threadIdx.x - off] : 0;
        __syncthreads();
        sm[threadIdx.x] += t;
        __syncthreads();
    }
    if (threadIdx.x < nb) bsums[threadIdx.x] = sm[threadIdx.x] - v;   // exclusive
}

__global__ void k_scan3(int* __restrict__ rowstart, const int* __restrict__ bsums, int N) {
    int i = blockIdx.x * 256 + threadIdx.x;
    if (i < N) rowstart[i] += bsums[blockIdx.x];
}

__global__ void k_scatter(const int* __restrict__ ei, const float* __restrict__ eattr,
                          const float* __restrict__ scal, const int* __restrict__ rowstart,
                          int* __restrict__ cursor, int2* __restrict__ csr, int E, int Etot) {
    int e = blockIdx.x * blockDim.x + threadIdx.x;
    if (e >= Etot) return;
    int s, d; float ea;
    if (e < E) { s = ei[e]; d = ei[E + e]; ea = eattr[e]; }
    else       { s = e - E; d = s;          ea = scal[1]; }
    int pos = atomicAdd(&cursor[d], 1);
    csr[rowstart[d] + pos] = make_int2(s, __float_as_int(ea));
}

// ---------- layer 1 GEMM: h1 = x @ W1, fused a_src1/a_dst1.  16 nodes per block ----------
__global__ void k_gemm1(const float* __restrict__ x, const float* __restrict__ W1,
                        const float* __restrict__ attsrc, const float* __restrict__ attdst,
                        float* __restrict__ h1, float* __restrict__ a_src, float* __restrict__ a_dst) {
    __shared__ float xs[16][FIN];   // 8 KB
    int n0 = blockIdx.x * 16;
    int t = threadIdx.x;
#pragma unroll
    for (int i = 0; i < 8; ++i) {
        int idx = t + i * 256;
        ((float*)xs)[idx] = x[(size_t)n0 * FIN + idx];
    }
    __syncthreads();
    float acc[16];
#pragma unroll
    for (int i = 0; i < 16; ++i) acc[i] = 0.0f;
#pragma unroll 4
    for (int k = 0; k < FIN; ++k) {
        float wv = W1[k * HC + t];
#pragma unroll
        for (int i = 0; i < 16; ++i) acc[i] += xs[i][k] * wv;
    }
    int g = t >> 6;   // head (wave id)
    float asr = attsrc[t], adr = attdst[t];
#pragma unroll
    for (int i = 0; i < 16; ++i) {
        h1[(size_t)(n0 + i) * HC + t] = acc[i];
        float ps = wredsum(acc[i] * asr);
        float pd = wredsum(acc[i] * adr);
        if ((t & 63) == 0) {
            a_src[(n0 + i) * H1 + g] = ps;
            a_dst[(n0 + i) * H1 + g] = pd;
        }
    }
}

// ---------- layer 1 aggregation: ONE WAVE PER NODE, float4 full-row gather ----------
// 4 nodes per 256-thread block; lane l covers channels 4l..4l+3 (head = l>>4)
__global__ void k_agg1(const int* __restrict__ rowstart, const int* __restrict__ deg,
                       const int2* __restrict__ csr,
                       const float* __restrict__ a_src, const float* __restrict__ a_dst,
                       const float* __restrict__ scal, const float* __restrict__ h1,
                       const float* __restrict__ b1, float* __restrict__ out1) {
    __shared__ float4 wlds[4][64];   // [wave][edge-in-chunk] per-head weights, 4 KB
    int wid = threadIdx.x >> 6, lane = threadIdx.x & 63;
    int n = blockIdx.x * 4 + wid;
    int myh = lane >> 4;
    int rs = rowstart[n], cnt = deg[n];
    const float4 adv = ((const float4*)a_dst)[n];
    const float4 wh  = *((const float4*)(scal + 4));
    const float4* h1v = (const float4*)h1;
    const float* wbase = (const float*)(&wlds[wid][0]) + myh;

    float4 M = make_float4(-INFINITY, -INFINITY, -INFINITY, -INFINITY);
    float4 den = make_float4(0.f, 0.f, 0.f, 0.f);
    float4 acc = make_float4(0.f, 0.f, 0.f, 0.f);

    for (int base = 0; base < cnt; base += 64) {
        int j = base + lane;
        int sj = 0;
        float4 al = make_float4(-INFINITY, -INFINITY, -INFINITY, -INFINITY);
        if (j < cnt) {
            int2 cv = csr[rs + j];
            sj = cv.x;
            float ea = __int_as_float(cv.y);
            float4 as4 = ((const float4*)a_src)[sj];
            al.x = as4.x + adv.x + ea * wh.x;
            al.y = as4.y + adv.y + ea * wh.y;
            al.z = as4.z + adv.z + ea * wh.z;
            al.w = as4.w + adv.w + ea * wh.w;
            al.x = al.x > 0.f ? al.x : NEG_SLOPE * al.x;
            al.y = al.y > 0.f ? al.y : NEG_SLOPE * al.y;
            al.z = al.z > 0.f ? al.z : NEG_SLOPE * al.z;
            al.w = al.w > 0.f ? al.w : NEG_SLOPE * al.w;
        }
        float4 cm = bcast4(wredmax4(al));
        float4 newM = make_float4(fmaxf(M.x, cm.x), fmaxf(M.y, cm.y),
                                  fmaxf(M.z, cm.z), fmaxf(M.w, cm.w));
        float4 sc = make_float4(__expf(M.x - newM.x), __expf(M.y - newM.y),
                                __expf(M.z - newM.z), __expf(M.w - newM.w));
        den.x *= sc.x; den.y *= sc.y; den.z *= sc.z; den.w *= sc.w;
        float scm = comp4(sc, myh);
        acc.x *= scm; acc.y *= scm; acc.z *= scm; acc.w *= scm;
        M = newM;
        float4 w4 = make_float4(__expf(al.x - M.x), __expf(al.y - M.y),
                                __expf(al.z - M.z), __expf(al.w - M.w));
        den.x += w4.x; den.y += w4.y; den.z += w4.z; den.w += w4.w;
        wlds[wid][lane] = w4;
        int m = min(64, cnt - base);
#pragma unroll 4
        for (int jj = 0; jj < m; ++jj) {
            int   s  = __shfl(sj, jj);
            float ww = wbase[jj * 4];              // LDS
            float4 hv = h1v[(size_t)s * 64 + lane];
            acc.x += hv.x * ww; acc.y += hv.y * ww;
            acc.z += hv.z * ww; acc.w += hv.w * ww;
        }
    }
    float4 dsum = bcast4(wredsum4(den));
    float dt = comp4(dsum, myh) + EPSF;
    float inv = 1.0f / dt;
    float4 b4 = ((const float4*)b1)[lane];
    float4 v;
    v.x = acc.x * inv + b4.x;
    v.y = acc.y * inv + b4.y;
    v.z = acc.z * inv + b4.z;
    v.w = acc.w * inv + b4.w;
    v.x = v.x > 0.f ? v.x : expm1f(v.x);
    v.y = v.y > 0.f ? v.y : expm1f(v.y);
    v.z = v.z > 0.f ? v.z : expm1f(v.z);
    v.w = v.w > 0.f ? v.w : expm1f(v.w);
    ((float4*)(out1 + (size_t)n * HC))[lane] = v;
}

// ---------- layer 2 GEMM: h2 = out1 @ W2, fused a_src2/a_dst2.  16 nodes per block ----------
__global__ void k_gemm2(const float* __restrict__ out1, const float* __restrict__ W2,
                        const float* __restrict__ attsrc, const float* __restrict__ attdst,
                        float* __restrict__ h2, float* __restrict__ a_src2, float* __restrict__ a_dst2) {
    __shared__ float rows[16][HC];   // 16 KB
    int n0 = blockIdx.x * 16;
    int t = threadIdx.x;
#pragma unroll
    for (int i = 0; i < 16; ++i) {
        int idx = t + i * 256;
        ((float*)rows)[idx] = out1[(size_t)n0 * HC + idx];
    }
    __syncthreads();
    int c = t & 63, g = t >> 6;   // wave g handles nodes g, g+4, g+8, g+12
    float acc[4] = {0, 0, 0, 0};
#pragma unroll 4
    for (int k = 0; k < HC; ++k) {
        float wv = W2[k * C + c];
#pragma unroll
        for (int q = 0; q < 4; ++q) acc[q] += rows[g + 4 * q][k] * wv;
    }
    float asr = attsrc[c], adr = attdst[c];
#pragma unroll
    for (int q = 0; q < 4; ++q) {
        int n = n0 + g + 4 * q;
        h2[(size_t)n * C + c] = acc[q];
        float ps = wredsum(acc[q] * asr);
        float pd = wredsum(acc[q] * adr);
        if (c == 0) { a_src2[n] = ps; a_dst2[n] = pd; }
    }
}

// ---------- layer 2 aggregation + classifier head: ONE WAVE PER NODE ----------
// lane = eg*16 + li : edge-subgroup eg (4 edges in flight), channel-quad li
__global__ void k_agg2(const int* __restrict__ rowstart, const int* __restrict__ deg,
                       const int2* __restrict__ csr,
                       const float* __restrict__ a_src2, const float* __restrict__ a_dst2,
                       const float* __restrict__ scal, const float* __restrict__ h2,
                       const float* __restrict__ b2, const float* __restrict__ Wfc,
                       const float* __restrict__ bfc, float* __restrict__ d_out, int N) {
    __shared__ float wlds[4][64];
    int wid = threadIdx.x >> 6, lane = threadIdx.x & 63;
    int n = blockIdx.x * 4 + wid;
    int eg = lane >> 4, li = lane & 15;
    int rs = rowstart[n], cnt = deg[n];
    float adv = a_dst2[n];
    float w2  = scal[2];
    const float4* h2v = (const float4*)h2;

    float M = -INFINITY, den = 0.0f;
    float4 acc = make_float4(0.f, 0.f, 0.f, 0.f);

    for (int base = 0; base < cnt; base += 64) {
        int j = base + lane;
        int sj = 0; float al = -INFINITY;
        if (j < cnt) {
            int2 cv = csr[rs + j];
            sj = cv.x;
            al = a_src2[sj] + adv + __int_as_float(cv.y) * w2;
            al = al > 0.0f ? al : NEG_SLOPE * al;
        }
        float cm = wredmax(al); cm = __shfl(cm, 0);
        float newM = fmaxf(M, cm);
        float sc = __expf(M - newM);
        den *= sc;
        acc.x *= sc; acc.y *= sc; acc.z *= sc; acc.w *= sc;
        M = newM;
        float w = __expf(al - M);
        den += w;
        wlds[wid][lane] = w;
        int m = min(64, cnt - base);
#pragma unroll 4
        for (int jj = 0; jj < m; jj += 4) {
            int idx = jj + eg;                     // <= 63 always
            float ww = wlds[wid][idx];             // 0 for padded edges
            int   s  = __shfl(sj, idx);
            float4 hv = h2v[(size_t)s * 16 + li];
            acc.x += hv.x * ww; acc.y += hv.y * ww;
            acc.z += hv.z * ww; acc.w += hv.w * ww;
        }
    }
    // reduce acc across the 4 edge-subgroups (lanes l, l+16, l+32, l+48)
#pragma unroll
    for (int off = 32; off >= 16; off >>= 1) {
        acc.x += __shfl_down(acc.x, off);
        acc.y += __shfl_down(acc.y, off);
        acc.z += __shfl_down(acc.z, off);
        acc.w += __shfl_down(acc.w, off);
    }
    float dt = wredsum(den); dt = __shfl(dt, 0);
    float inv = 1.0f / (dt + EPSF);
    float4 b4 = ((const float4*)b2)[li];
    float4 v;
    v.x = acc.x * inv + b4.x;
    v.y = acc.y * inv + b4.y;
    v.z = acc.z * inv + b4.z;
    v.w = acc.w * inv + b4.w;
    v.x = v.x > 0.f ? v.x : expm1f(v.x);
    v.y = v.y > 0.f ? v.y : expm1f(v.y);
    v.z = v.z > 0.f ? v.z : expm1f(v.z);
    v.w = v.w > 0.f ? v.w : expm1f(v.w);
    if (lane < 16)
        ((float4*)(d_out + (size_t)2 * N + (size_t)n * C))[li] = v;   // emb
    // classifier: channels 4li..4li+3 on lanes 0..15
    const float4* wfc4 = (const float4*)Wfc;
    float4 A = wfc4[li * 2], B = wfc4[li * 2 + 1];
    float p0 = v.x * A.x + v.y * A.z + v.z * B.x + v.w * B.z;
    float p1 = v.x * A.y + v.y * A.w + v.z * B.y + v.w * B.w;
#pragma unroll
    for (int off = 8; off; off >>= 1) {
        p0 += __shfl_down(p0, off);
        p1 += __shfl_down(p1, off);
    }
    if (lane == 0) {
        p0 += bfc[0]; p1 += bfc[1];
        float mm = fmaxf(p0, p1);
        float lse = mm + logf(__expf(p0 - mm) + __expf(p1 - mm));
        d_out[(size_t)n * 2]     = p0 - lse;
        d_out[(size_t)n * 2 + 1] = p1 - lse;
    }
}

extern "C" void kernel_launch(void* const* d_in, const int* in_sizes, int n_in,
                              void* d_out, int out_size, void* d_ws, size_t ws_size,
                              hipStream_t stream) {
    const float* x     = (const float*)d_in[0];
    const int*   ei    = (const int*)  d_in[1];
    const float* eattr = (const float*)d_in[2];
    const float* W1    = (const float*)d_in[3];
    const float* as1   = (const float*)d_in[4];
    const float* ad1   = (const float*)d_in[5];
    const float* We1   = (const float*)d_in[6];
    const float* ae1   = (const float*)d_in[7];
    const float* b1    = (const float*)d_in[8];
    const float* W2    = (const float*)d_in[9];
    const float* as2   = (const float*)d_in[10];
    const float* ad2   = (const float*)d_in[11];
    const float* We2   = (const float*)d_in[12];
    const float* ae2   = (const float*)d_in[13];
    const float* b2    = (const float*)d_in[14];
    const float* Wfc   = (const float*)d_in[15];
    const float* bfc   = (const float*)d_in[16];

    const int N    = in_sizes[0] / FIN;   // 50000
    const int E    = in_sizes[2];         // 800000
    const int Etot = E + N;

    char* wsb = (char*)d_ws;
    size_t off = 0;
    auto alloc = [&](size_t elems) {
        off = (off + 15) & ~(size_t)15;   // 16B align every buffer (float4 loads)
        void* p = wsb + off; off += elems * 4; return p;
    };

    // ---- zero-initialized region (front) ----
    int*   deg    = (int*)  alloc(N);
    int*   cursor = (int*)  alloc(N);
    float* scal   = (float*)alloc(8);
    size_t zero_bytes = (off + 15) & ~(size_t)15;
    // ---- rest ----
    int*   rowstart = (int*)  alloc(N);
    int*   bsums    = (int*)  alloc(256);
    int2*  csr      = (int2*) alloc((size_t)Etot * 2);
    float* h1       = (float*)alloc((size_t)N * HC);
    float* out1     = (float*)alloc((size_t)N * HC);
    float* h2       = (float*)alloc((size_t)N * C);
    float* a_src1   = (float*)alloc((size_t)N * H1);
    float* a_dst1   = (float*)alloc((size_t)N * H1);
    float* a_src2   = (float*)alloc(N);
    float* a_dst2   = (float*)alloc(N);

    hipMemsetAsync(d_ws, 0, zero_bytes, stream);

    k_ea_sum<<<(E + 255) / 256, 256, 0, stream>>>(eattr, E, scal);
    k_prep<<<1, 256, 0, stream>>>(We1, ae1, We2, ae2, scal, 1.0f / (float)E);

    int ge = (Etot + 255) / 256;
    int nb = (N + 255) / 256;
    k_hist<<<ge, 256, 0, stream>>>(ei, deg, E, Etot);
    k_scan1<<<nb, 256, 0, stream>>>(deg, rowstart, bsums, N);
    k_scan2<<<1, 256, 0, stream>>>(bsums, nb);
    k_scan3<<<nb, 256, 0, stream>>>(rowstart, bsums, N);
    k_scatter<<<ge, 256, 0, stream>>>(ei, eattr, scal, rowstart, cursor, csr, E, Etot);

    k_gemm1<<<N / 16, 256, 0, stream>>>(x, W1, as1, ad1, h1, a_src1, a_dst1);
    k_agg1<<<N / 4, 256, 0, stream>>>(rowstart, deg, csr, a_src1, a_dst1, scal, h1, b1, out1);
    k_gemm2<<<N / 16, 256, 0, stream>>>(out1, W2, as2, ad2, h2, a_src2, a_dst2);
    k_agg2<<<N / 4, 256, 0, stream>>>(rowstart, deg, csr, a_src2, a_dst2, scal, h2,
                                      b2, Wfc, bfc, (float*)d_out, N);
}

// Round 6
// 493.710 us; speedup vs baseline: 3.5403x; 1.1127x over previous
//
#include <hip/hip_runtime.h>
#include <math.h>

#define NEG_SLOPE 0.2f
#define EPSF 1e-16f

constexpr int FIN = 128;
constexpr int H1  = 4;
constexpr int C   = 64;
constexpr int HC  = 256;   // H1 * C

__device__ inline float wredsum(float v) {
#pragma unroll
    for (int off = 32; off; off >>= 1) v += __shfl_down(v, off);
    return v;
}
__device__ inline float wredmax(float v) {
#pragma unroll
    for (int off = 32; off; off >>= 1) v = fmaxf(v, __shfl_down(v, off));
    return v;
}
__device__ inline float4 wredmax4(float4 v) {
#pragma unroll
    for (int off = 32; off; off >>= 1) {
        v.x = fmaxf(v.x, __shfl_down(v.x, off));
        v.y = fmaxf(v.y, __shfl_down(v.y, off));
        v.z = fmaxf(v.z, __shfl_down(v.z, off));
        v.w = fmaxf(v.w, __shfl_down(v.w, off));
    }
    return v;
}
__device__ inline float4 wredsum4(float4 v) {
#pragma unroll
    for (int off = 32; off; off >>= 1) {
        v.x += __shfl_down(v.x, off);
        v.y += __shfl_down(v.y, off);
        v.z += __shfl_down(v.z, off);
        v.w += __shfl_down(v.w, off);
    }
    return v;
}
__device__ inline float4 bcast4(float4 v) {
    v.x = __shfl(v.x, 0); v.y = __shfl(v.y, 0);
    v.z = __shfl(v.z, 0); v.w = __shfl(v.w, 0);
    return v;
}
__device__ inline float comp4(float4 v, int i) {
    return i == 0 ? v.x : (i == 1 ? v.y : (i == 2 ? v.z : v.w));
}
__device__ inline unsigned short f2bf(float f) {   // RNE
    unsigned u = __float_as_uint(f);
    return (unsigned short)((u + 0x7fffu + ((u >> 16) & 1u)) >> 16);
}

// ---------- tiny prep ----------
__global__ void k_ea_sum(const float* __restrict__ ea, int E, float* __restrict__ scal) {
    int i = blockIdx.x * blockDim.x + threadIdx.x;
    float v = (i < E) ? ea[i] : 0.0f;
    v = wredsum(v);
    __shared__ float sm[4];
    if ((threadIdx.x & 63) == 0) sm[threadIdx.x >> 6] = v;
    __syncthreads();
    if (threadIdx.x == 0) atomicAdd(scal, sm[0] + sm[1] + sm[2] + sm[3]);
}

// scal[1]=ea_mean, scal[2]=we2dot, scal[4..7]=we1dot[h]
__global__ void k_prep(const float* __restrict__ We1, const float* __restrict__ ae1,
                       const float* __restrict__ We2, const float* __restrict__ ae2,
                       float* __restrict__ scal, float inv_E) {
    int t = threadIdx.x;
    float p = We1[t] * ae1[t];
    p = wredsum(p);
    if ((t & 63) == 0) scal[4 + (t >> 6)] = p;
    if (t < 64) {
        float q = We2[t] * ae2[t];
        q = wredsum(q);
        if (t == 0) scal[2] = q;
    }
    if (t == 0) scal[1] = scal[0] * inv_E;
}

// ---------- CSR build (edges grouped by dst) ----------
__global__ void k_hist(const int* __restrict__ ei, int* __restrict__ deg, int E, int Etot) {
    int e = blockIdx.x * blockDim.x + threadIdx.x;
    if (e >= Etot) return;
    int d = (e < E) ? ei[E + e] : e - E;
    atomicAdd(&deg[d], 1);
}

__global__ void k_scan1(const int* __restrict__ deg, int* __restrict__ rowstart,
                        int* __restrict__ bsums, int N) {
    __shared__ int sm[256];
    int i = blockIdx.x * 256 + threadIdx.x;
    int v = (i < N) ? deg[i] : 0;
    sm[threadIdx.x] = v;
    __syncthreads();
    for (int off = 1; off < 256; off <<= 1) {
        int t = (threadIdx.x >= off) ? sm[threadIdx.x - off] : 0;
        __syncthreads();
        sm[threadIdx.x] += t;
        __syncthreads();
    }
    if (i < N) rowstart[i] = sm[threadIdx.x] - v;   // exclusive
    if (threadIdx.x == 255) bsums[blockIdx.x] = sm[255];
}

__global__ void k_scan2(int* __restrict__ bsums, int nb) {
    __shared__ int sm[256];
    int v = (threadIdx.x < nb) ? bsums[threadIdx.x] : 0;
    sm[threadIdx.x] = v;
    __syncthreads();
    for (int off = 1; off < 256; off <<= 1) {
        int t = (threadIdx.x >= off) ? sm[threadIdx.x - off] : 0;
        __syncthreads();
        sm[threadIdx.x] += t;
        __syncthreads();
    }
    if (threadIdx.x < nb) bsums[threadIdx.x] = sm[threadIdx.x] - v;   // exclusive
}

__global__ void k_scan3(int* __restrict__ rowstart, const int* __restrict__ bsums, int N) {
    int i = blockIdx.x * 256 + threadIdx.x;
    if (i < N) rowstart[i] += bsums[blockIdx.x];
}

__global__ void k_scatter(const int* __restrict__ ei, const float* __restrict__ eattr,
                          const float* __restrict__ scal, const int* __restrict__ rowstart,
                          int* __restrict__ cursor, int2* __restrict__ csr, int E, int Etot) {
    int e = blockIdx.x * blockDim.x + threadIdx.x;
    if (e >= Etot) return;
    int s, d; float ea;
    if (e < E) { s = ei[e]; d = ei[E + e]; ea = eattr[e]; }
    else       { s = e - E; d = s;          ea = scal[1]; }
    int pos = atomicAdd(&cursor[d], 1);
    csr[rowstart[d] + pos] = make_int2(s, __float_as_int(ea));
}

// ---------- layer 1 GEMM: h1(bf16) = x @ W1, fused a_src1/a_dst1.  16 nodes per block ----------
__global__ void k_gemm1(const float* __restrict__ x, const float* __restrict__ W1,
                        const float* __restrict__ attsrc, const float* __restrict__ attdst,
                        unsigned short* __restrict__ h1b,
                        float* __restrict__ a_src, float* __restrict__ a_dst) {
    __shared__ float xs[16][FIN];   // 8 KB
    int n0 = blockIdx.x * 16;
    int t = threadIdx.x;
#pragma unroll
    for (int i = 0; i < 8; ++i) {
        int idx = t + i * 256;
        ((float*)xs)[idx] = x[(size_t)n0 * FIN + idx];
    }
    __syncthreads();
    float acc[16];
#pragma unroll
    for (int i = 0; i < 16; ++i) acc[i] = 0.0f;
#pragma unroll 4
    for (int k = 0; k < FIN; ++k) {
        float wv = W1[k * HC + t];
#pragma unroll
        for (int i = 0; i < 16; ++i) acc[i] += xs[i][k] * wv;
    }
    int g = t >> 6;   // head (wave id)
    float asr = attsrc[t], adr = attdst[t];
#pragma unroll
    for (int i = 0; i < 16; ++i) {
        h1b[(size_t)(n0 + i) * HC + t] = f2bf(acc[i]);
        float ps = wredsum(acc[i] * asr);
        float pd = wredsum(acc[i] * adr);
        if ((t & 63) == 0) {
            a_src[(n0 + i) * H1 + g] = ps;
            a_dst[(n0 + i) * H1 + g] = pd;
        }
    }
}

// ---------- layer 1 aggregation: ONE WAVE PER NODE, bf16 row gather (uint2/lane) ----------
// 4 nodes per 256-thread block; lane l covers channels 4l..4l+3 (head = l>>4)
__global__ void k_agg1(const int* __restrict__ rowstart, const int* __restrict__ deg,
                       const int2* __restrict__ csr,
                       const float* __restrict__ a_src, const float* __restrict__ a_dst,
                       const float* __restrict__ scal, const unsigned short* __restrict__ h1b,
                       const float* __restrict__ b1, float* __restrict__ out1) {
    __shared__ float4 wlds[4][64];   // [wave][edge-in-chunk] per-head weights, 4 KB
    int wid = threadIdx.x >> 6, lane = threadIdx.x & 63;
    int n = blockIdx.x * 4 + wid;
    int myh = lane >> 4;
    int rs = rowstart[n], cnt = deg[n];
    const float4 adv = ((const float4*)a_dst)[n];
    const float4 wh  = *((const float4*)(scal + 4));
    const uint2* h1v = (const uint2*)h1b;         // row stride = 64 uint2
    const float* wbase = (const float*)(&wlds[wid][0]) + myh;

    float4 M = make_float4(-INFINITY, -INFINITY, -INFINITY, -INFINITY);
    float4 den  = make_float4(0.f, 0.f, 0.f, 0.f);
    float4 acc0 = make_float4(0.f, 0.f, 0.f, 0.f);
    float4 acc1 = make_float4(0.f, 0.f, 0.f, 0.f);

    for (int base = 0; base < cnt; base += 64) {
        int j = base + lane;
        int sj = 0;
        float4 al = make_float4(-INFINITY, -INFINITY, -INFINITY, -INFINITY);
        if (j < cnt) {
            int2 cv = csr[rs + j];
            sj = cv.x;
            float ea = __int_as_float(cv.y);
            float4 as4 = ((const float4*)a_src)[sj];
            al.x = as4.x + adv.x + ea * wh.x;
            al.y = as4.y + adv.y + ea * wh.y;
            al.z = as4.z + adv.z + ea * wh.z;
            al.w = as4.w + adv.w + ea * wh.w;
            al.x = al.x > 0.f ? al.x : NEG_SLOPE * al.x;
            al.y = al.y > 0.f ? al.y : NEG_SLOPE * al.y;
            al.z = al.z > 0.f ? al.z : NEG_SLOPE * al.z;
            al.w = al.w > 0.f ? al.w : NEG_SLOPE * al.w;
        }
        float4 cm = bcast4(wredmax4(al));
        float4 newM = make_float4(fmaxf(M.x, cm.x), fmaxf(M.y, cm.y),
                                  fmaxf(M.z, cm.z), fmaxf(M.w, cm.w));
        float4 sc = make_float4(__expf(M.x - newM.x), __expf(M.y - newM.y),
                                __expf(M.z - newM.z), __expf(M.w - newM.w));
        den.x *= sc.x; den.y *= sc.y; den.z *= sc.z; den.w *= sc.w;
        float scm = comp4(sc, myh);
        acc0.x *= scm; acc0.y *= scm; acc0.z *= scm; acc0.w *= scm;
        acc1.x *= scm; acc1.y *= scm; acc1.z *= scm; acc1.w *= scm;
        M = newM;
        float4 w4 = make_float4(__expf(al.x - M.x), __expf(al.y - M.y),
                                __expf(al.z - M.z), __expf(al.w - M.w));
        den.x += w4.x; den.y += w4.y; den.z += w4.z; den.w += w4.w;
        wlds[wid][lane] = w4;
        int m = min(64, cnt - base);
        int jj = 0;
#pragma unroll 2
        for (; jj + 1 < m; jj += 2) {
            int s0 = __shfl(sj, jj);
            int s1 = __shfl(sj, jj + 1);
            float w0 = wbase[jj * 4];
            float w1 = wbase[jj * 4 + 4];
            uint2 v0 = h1v[(size_t)s0 * 64 + lane];
            uint2 v1 = h1v[(size_t)s1 * 64 + lane];
            acc0.x += __uint_as_float(v0.x << 16)          * w0;
            acc0.y += __uint_as_float(v0.x & 0xffff0000u)  * w0;
            acc0.z += __uint_as_float(v0.y << 16)          * w0;
            acc0.w += __uint_as_float(v0.y & 0xffff0000u)  * w0;
            acc1.x += __uint_as_float(v1.x << 16)          * w1;
            acc1.y += __uint_as_float(v1.x & 0xffff0000u)  * w1;
            acc1.z += __uint_as_float(v1.y << 16)          * w1;
            acc1.w += __uint_as_float(v1.y & 0xffff0000u)  * w1;
        }
        if (jj < m) {
            int s0 = __shfl(sj, jj);
            float w0 = wbase[jj * 4];
            uint2 v0 = h1v[(size_t)s0 * 64 + lane];
            acc0.x += __uint_as_float(v0.x << 16)          * w0;
            acc0.y += __uint_as_float(v0.x & 0xffff0000u)  * w0;
            acc0.z += __uint_as_float(v0.y << 16)          * w0;
            acc0.w += __uint_as_float(v0.y & 0xffff0000u)  * w0;
        }
    }
    float4 dsum = bcast4(wredsum4(den));
    float dt = comp4(dsum, myh) + EPSF;
    float inv = 1.0f / dt;
    float4 b4 = ((const float4*)b1)[lane];
    float4 v;
    v.x = (acc0.x + acc1.x) * inv + b4.x;
    v.y = (acc0.y + acc1.y) * inv + b4.y;
    v.z = (acc0.z + acc1.z) * inv + b4.z;
    v.w = (acc0.w + acc1.w) * inv + b4.w;
    v.x = v.x > 0.f ? v.x : expm1f(v.x);
    v.y = v.y > 0.f ? v.y : expm1f(v.y);
    v.z = v.z > 0.f ? v.z : expm1f(v.z);
    v.w = v.w > 0.f ? v.w : expm1f(v.w);
    ((float4*)(out1 + (size_t)n * HC))[lane] = v;
}

// ---------- layer 2 GEMM: h2 = out1 @ W2, fused a_src2/a_dst2.  16 nodes per block ----------
__global__ void k_gemm2(const float* __restrict__ out1, const float* __restrict__ W2,
                        const float* __restrict__ attsrc, const float* __restrict__ attdst,
                        float* __restrict__ h2, float* __restrict__ a_src2, float* __restrict__ a_dst2) {
    __shared__ float rows[16][HC];   // 16 KB
    int n0 = blockIdx.x * 16;
    int t = threadIdx.x;
#pragma unroll
    for (int i = 0; i < 16; ++i) {
        int idx = t + i * 256;
        ((float*)rows)[idx] = out1[(size_t)n0 * HC + idx];
    }
    __syncthreads();
    int c = t & 63, g = t >> 6;   // wave g handles nodes g, g+4, g+8, g+12
    float acc[4] = {0, 0, 0, 0};
#pragma unroll 4
    for (int k = 0; k < HC; ++k) {
        float wv = W2[k * C + c];
#pragma unroll
        for (int q = 0; q < 4; ++q) acc[q] += rows[g + 4 * q][k] * wv;
    }
    float asr = attsrc[c], adr = attdst[c];
#pragma unroll
    for (int q = 0; q < 4; ++q) {
        int n = n0 + g + 4 * q;
        h2[(size_t)n * C + c] = acc[q];
        float ps = wredsum(acc[q] * asr);
        float pd = wredsum(acc[q] * adr);
        if (c == 0) { a_src2[n] = ps; a_dst2[n] = pd; }
    }
}

// ---------- layer 2 aggregation + classifier head: ONE WAVE PER NODE ----------
// lane = eg*16 + li : edge-subgroup eg (4 edges in flight), channel-quad li
__global__ void k_agg2(const int* __restrict__ rowstart, const int* __restrict__ deg,
                       const int2* __restrict__ csr,
                       const float* __restrict__ a_src2, const float* __restrict__ a_dst2,
                       const float* __restrict__ scal, const float* __restrict__ h2,
                       const float* __restrict__ b2, const float* __restrict__ Wfc,
                       const float* __restrict__ bfc, float* __restrict__ d_out, int N) {
    __shared__ float wlds[4][64];
    int wid = threadIdx.x >> 6, lane = threadIdx.x & 63;
    int n = blockIdx.x * 4 + wid;
    int eg = lane >> 4, li = lane & 15;
    int rs = rowstart[n], cnt = deg[n];
    float adv = a_dst2[n];
    float w2  = scal[2];
    const float4* h2v = (const float4*)h2;

    float M = -INFINITY, den = 0.0f;
    float4 acc = make_float4(0.f, 0.f, 0.f, 0.f);

    for (int base = 0; base < cnt; base += 64) {
        int j = base + lane;
        int sj = 0; float al = -INFINITY;
        if (j < cnt) {
            int2 cv = csr[rs + j];
            sj = cv.x;
            al = a_src2[sj] + adv + __int_as_float(cv.y) * w2;
            al = al > 0.0f ? al : NEG_SLOPE * al;
        }
        float cm = wredmax(al); cm = __shfl(cm, 0);
        float newM = fmaxf(M, cm);
        float sc = __expf(M - newM);
        den *= sc;
        acc.x *= sc; acc.y *= sc; acc.z *= sc; acc.w *= sc;
        M = newM;
        float w = __expf(al - M);
        den += w;
        wlds[wid][lane] = w;
        int m = min(64, cnt - base);
#pragma unroll 4
        for (int jj = 0; jj < m; jj += 4) {
            int idx = jj + eg;                     // <= 63 always
            float ww = wlds[wid][idx];             // 0 for padded edges
            int   s  = __shfl(sj, idx);
            float4 hv = h2v[(size_t)s * 16 + li];
            acc.x += hv.x * ww; acc.y += hv.y * ww;
            acc.z += hv.z * ww; acc.w += hv.w * ww;
        }
    }
    // reduce acc across the 4 edge-subgroups (lanes l, l+16, l+32, l+48)
#pragma unroll
    for (int off = 32; off >= 16; off >>= 1) {
        acc.x += __shfl_down(acc.x, off);
        acc.y += __shfl_down(acc.y, off);
        acc.z += __shfl_down(acc.z, off);
        acc.w += __shfl_down(acc.w, off);
    }
    float dt = wredsum(den); dt = __shfl(dt, 0);
    float inv = 1.0f / (dt + EPSF);
    float4 b4 = ((const float4*)b2)[li];
    float4 v;
    v.x = acc.x * inv + b4.x;
    v.y = acc.y * inv + b4.y;
    v.z = acc.z * inv + b4.z;
    v.w = acc.w * inv + b4.w;
    v.x = v.x > 0.f ? v.x : expm1f(v.x);
    v.y = v.y > 0.f ? v.y : expm1f(v.y);
    v.z = v.z > 0.f ? v.z : expm1f(v.z);
    v.w = v.w > 0.f ? v.w : expm1f(v.w);
    if (lane < 16)
        ((float4*)(d_out + (size_t)2 * N + (size_t)n * C))[li] = v;   // emb
    // classifier: channels 4li..4li+3 on lanes 0..15
    const float4* wfc4 = (const float4*)Wfc;
    float4 A = wfc4[li * 2], B = wfc4[li * 2 + 1];
    float p0 = v.x * A.x + v.y * A.z + v.z * B.x + v.w * B.z;
    float p1 = v.x * A.y + v.y * A.w + v.z * B.y + v.w * B.w;
#pragma unroll
    for (int off = 8; off; off >>= 1) {
        p0 += __shfl_down(p0, off);
        p1 += __shfl_down(p1, off);
    }
    if (lane == 0) {
        p0 += bfc[0]; p1 += bfc[1];
        float mm = fmaxf(p0, p1);
        float lse = mm + logf(__expf(p0 - mm) + __expf(p1 - mm));
        d_out[(size_t)n * 2]     = p0 - lse;
        d_out[(size_t)n * 2 + 1] = p1 - lse;
    }
}

extern "C" void kernel_launch(void* const* d_in, const int* in_sizes, int n_in,
                              void* d_out, int out_size, void* d_ws, size_t ws_size,
                              hipStream_t stream) {
    const float* x     = (const float*)d_in[0];
    const int*   ei    = (const int*)  d_in[1];
    const float* eattr = (const float*)d_in[2];
    const float* W1    = (const float*)d_in[3];
    const float* as1   = (const float*)d_in[4];
    const float* ad1   = (const float*)d_in[5];
    const float* We1   = (const float*)d_in[6];
    const float* ae1   = (const float*)d_in[7];
    const float* b1    = (const float*)d_in[8];
    const float* W2    = (const float*)d_in[9];
    const float* as2   = (const float*)d_in[10];
    const float* ad2   = (const float*)d_in[11];
    const float* We2   = (const float*)d_in[12];
    const float* ae2   = (const float*)d_in[13];
    const float* b2    = (const float*)d_in[14];
    const float* Wfc   = (const float*)d_in[15];
    const float* bfc   = (const float*)d_in[16];

    const int N    = in_sizes[0] / FIN;   // 50000
    const int E    = in_sizes[2];         // 800000
    const int Etot = E + N;

    char* wsb = (char*)d_ws;
    size_t off = 0;
    auto alloc = [&](size_t elems) {
        off = (off + 15) & ~(size_t)15;   // 16B align every buffer
        void* p = wsb + off; off += elems * 4; return p;
    };

    // ---- zero-initialized region (front) ----
    int*   deg    = (int*)  alloc(N);
    int*   cursor = (int*)  alloc(N);
    float* scal   = (float*)alloc(8);
    size_t zero_bytes = (off + 15) & ~(size_t)15;
    // ---- rest ----
    int*   rowstart = (int*)  alloc(N);
    int*   bsums    = (int*)  alloc(256);
    int2*  csr      = (int2*) alloc((size_t)Etot * 2);
    unsigned short* h1b = (unsigned short*)alloc((size_t)N * HC / 2);   // bf16
    float* out1     = (float*)alloc((size_t)N * HC);
    float* h2       = (float*)alloc((size_t)N * C);
    float* a_src1   = (float*)alloc((size_t)N * H1);
    float* a_dst1   = (float*)alloc((size_t)N * H1);
    float* a_src2   = (float*)alloc(N);
    float* a_dst2   = (float*)alloc(N);

    hipMemsetAsync(d_ws, 0, zero_bytes, stream);

    k_ea_sum<<<(E + 255) / 256, 256, 0, stream>>>(eattr, E, scal);
    k_prep<<<1, 256, 0, stream>>>(We1, ae1, We2, ae2, scal, 1.0f / (float)E);

    int ge = (Etot + 255) / 256;
    int nb = (N + 255) / 256;
    k_hist<<<ge, 256, 0, stream>>>(ei, deg, E, Etot);
    k_scan1<<<nb, 256, 0, stream>>>(deg, rowstart, bsums, N);
    k_scan2<<<1, 256, 0, stream>>>(bsums, nb);
    k_scan3<<<nb, 256, 0, stream>>>(rowstart, bsums, N);
    k_scatter<<<ge, 256, 0, stream>>>(ei, eattr, scal, rowstart, cursor, csr, E, Etot);

    k_gemm1<<<N / 16, 256, 0, stream>>>(x, W1, as1, ad1, h1b, a_src1, a_dst1);
    k_agg1<<<N / 4, 256, 0, stream>>>(rowstart, deg, csr, a_src1, a_dst1, scal, h1b, b1, out1);
    k_gemm2<<<N / 16, 256, 0, stream>>>(out1, W2, as2, ad2, h2, a_src2, a_dst2);
    k_agg2<<<N / 4, 256, 0, stream>>>(rowstart, deg, csr, a_src2, a_dst2, scal, h2,
                                      b2, Wfc, bfc, (float*)d_out, N);
}

// Round 7
// 486.456 us; speedup vs baseline: 3.5931x; 1.0149x over previous
//
#include <hip/hip_runtime.h>
#include <math.h>

#define NEG_SLOPE 0.2f
#define EPSF 1e-16f

constexpr int FIN = 128;
constexpr int H1  = 4;
constexpr int C   = 64;
constexpr int HC  = 256;   // H1 * C

__device__ inline float wredsum(float v) {
#pragma unroll
    for (int off = 32; off; off >>= 1) v += __shfl_down(v, off);
    return v;
}
__device__ inline float wredmax(float v) {
#pragma unroll
    for (int off = 32; off; off >>= 1) v = fmaxf(v, __shfl_down(v, off));
    return v;
}
__device__ inline float4 wredmax4(float4 v) {
#pragma unroll
    for (int off = 32; off; off >>= 1) {
        v.x = fmaxf(v.x, __shfl_down(v.x, off));
        v.y = fmaxf(v.y, __shfl_down(v.y, off));
        v.z = fmaxf(v.z, __shfl_down(v.z, off));
        v.w = fmaxf(v.w, __shfl_down(v.w, off));
    }
    return v;
}
__device__ inline float4 wredsum4(float4 v) {
#pragma unroll
    for (int off = 32; off; off >>= 1) {
        v.x += __shfl_down(v.x, off);
        v.y += __shfl_down(v.y, off);
        v.z += __shfl_down(v.z, off);
        v.w += __shfl_down(v.w, off);
    }
    return v;
}
__device__ inline float4 bcast4(float4 v) {
    v.x = __shfl(v.x, 0); v.y = __shfl(v.y, 0);
    v.z = __shfl(v.z, 0); v.w = __shfl(v.w, 0);
    return v;
}
__device__ inline float comp4(float4 v, int i) {
    return i == 0 ? v.x : (i == 1 ? v.y : (i == 2 ? v.z : v.w));
}
__device__ inline unsigned short f2bf(float f) {   // RNE
    unsigned u = __float_as_uint(f);
    return (unsigned short)((u + 0x7fffu + ((u >> 16) & 1u)) >> 16);
}

// ---------- tiny prep ----------
__global__ void k_ea_sum(const float* __restrict__ ea, int E, float* __restrict__ scal) {
    int i = blockIdx.x * blockDim.x + threadIdx.x;
    float v = (i < E) ? ea[i] : 0.0f;
    v = wredsum(v);
    __shared__ float sm[4];
    if ((threadIdx.x & 63) == 0) sm[threadIdx.x >> 6] = v;
    __syncthreads();
    if (threadIdx.x == 0) atomicAdd(scal, sm[0] + sm[1] + sm[2] + sm[3]);
}

// scal[1]=ea_mean, scal[2]=we2dot, scal[4..7]=we1dot[h]
__global__ void k_prep(const float* __restrict__ We1, const float* __restrict__ ae1,
                       const float* __restrict__ We2, const float* __restrict__ ae2,
                       float* __restrict__ scal, float inv_E) {
    int t = threadIdx.x;
    float p = We1[t] * ae1[t];
    p = wredsum(p);
    if ((t & 63) == 0) scal[4 + (t >> 6)] = p;
    if (t < 64) {
        float q = We2[t] * ae2[t];
        q = wredsum(q);
        if (t == 0) scal[2] = q;
    }
    if (t == 0) scal[1] = scal[0] * inv_E;
}

// reorder weights: W1r[k/4][n][4], W2r[k/4][c][4]  (one float4 = 4 consecutive k-taps)
__global__ void k_reord(const float* __restrict__ W1, const float* __restrict__ W2,
                        float* __restrict__ W1r, float* __restrict__ W2r) {
    int idx = blockIdx.x * 256 + threadIdx.x;
    if (idx < FIN * HC) {
        int k = idx / HC, n = idx % HC;
        W1r[(((k >> 2) * HC) + n) * 4 + (k & 3)] = W1[idx];
    }
    if (idx < HC * C) {
        int k = idx / C, c = idx % C;
        W2r[(((k >> 2) * C) + c) * 4 + (k & 3)] = W2[idx];
    }
}

// ---------- CSR build (edges grouped by dst) ----------
__global__ void k_hist(const int* __restrict__ ei, int* __restrict__ deg, int E, int Etot) {
    int e = blockIdx.x * blockDim.x + threadIdx.x;
    if (e >= Etot) return;
    int d = (e < E) ? ei[E + e] : e - E;
    atomicAdd(&deg[d], 1);
}

__global__ void k_scan1(const int* __restrict__ deg, int* __restrict__ rowstart,
                        int* __restrict__ bsums, int N) {
    __shared__ int sm[256];
    int i = blockIdx.x * 256 + threadIdx.x;
    int v = (i < N) ? deg[i] : 0;
    sm[threadIdx.x] = v;
    __syncthreads();
    for (int off = 1; off < 256; off <<= 1) {
        int t = (threadIdx.x >= off) ? sm[threadIdx.x - off] : 0;
        __syncthreads();
        sm[threadIdx.x] += t;
        __syncthreads();
    }
    if (i < N) rowstart[i] = sm[threadIdx.x] - v;   // exclusive
    if (threadIdx.x == 255) bsums[blockIdx.x] = sm[255];
}

__global__ void k_scan2(int* __restrict__ bsums, int nb) {
    __shared__ int sm[256];
    int v = (threadIdx.x < nb) ? bsums[threadIdx.x] : 0;
    sm[threadIdx.x] = v;
    __syncthreads();
    for (int off = 1; off < 256; off <<= 1) {
        int t = (threadIdx.x >= off) ? sm[threadIdx.x - off] : 0;
        __syncthreads();
        sm[threadIdx.x] += t;
        __syncthreads();
    }
    if (threadIdx.x < nb) bsums[threadIdx.x] = sm[threadIdx.x] - v;   // exclusive
}

__global__ void k_scan3(int* __restrict__ rowstart, const int* __restrict__ bsums, int N) {
    int i = blockIdx.x * 256 + threadIdx.x;
    if (i < N) rowstart[i] += bsums[blockIdx.x];
}

__global__ void k_scatter(const int* __restrict__ ei, const float* __restrict__ eattr,
                          const float* __restrict__ scal, const int* __restrict__ rowstart,
                          int* __restrict__ cursor, int2* __restrict__ csr, int E, int Etot) {
    int e = blockIdx.x * blockDim.x + threadIdx.x;
    if (e >= Etot) return;
    int s, d; float ea;
    if (e < E) { s = ei[e]; d = ei[E + e]; ea = eattr[e]; }
    else       { s = e - E; d = s;          ea = scal[1]; }
    int pos = atomicAdd(&cursor[d], 1);
    csr[rowstart[d] + pos] = make_int2(s, __float_as_int(ea));
}

// ---------- layer 1 GEMM: h1(bf16) = x @ W1, fused a_src1/a_dst1.  16 nodes per block ----------
__global__ void k_gemm1(const float* __restrict__ x, const float4* __restrict__ W1r,
                        const float* __restrict__ attsrc, const float* __restrict__ attdst,
                        unsigned short* __restrict__ h1b,
                        float* __restrict__ a_src, float* __restrict__ a_dst) {
    __shared__ float xs[16][FIN];   // 8 KB
    int n0 = blockIdx.x * 16;
    int t = threadIdx.x;
    {
        float4* xs4 = (float4*)xs;
        const float4* xg = (const float4*)(x + (size_t)n0 * FIN);
        xs4[t]       = xg[t];
        xs4[t + 256] = xg[t + 256];
    }
    __syncthreads();
    float acc[16];
#pragma unroll
    for (int i = 0; i < 16; ++i) acc[i] = 0.0f;
#pragma unroll 4
    for (int k4 = 0; k4 < FIN / 4; ++k4) {
        float4 wv = W1r[k4 * HC + t];
#pragma unroll
        for (int i = 0; i < 16; ++i) {
            float4 xv = *(const float4*)(&xs[i][k4 * 4]);
            acc[i] = fmaf(xv.x, wv.x, fmaf(xv.y, wv.y,
                     fmaf(xv.z, wv.z, fmaf(xv.w, wv.w, acc[i]))));
        }
    }
    int g = t >> 6;   // head (wave id)
    float asr = attsrc[t], adr = attdst[t];
#pragma unroll
    for (int i = 0; i < 16; ++i) {
        h1b[(size_t)(n0 + i) * HC + t] = f2bf(acc[i]);
        float ps = wredsum(acc[i] * asr);
        float pd = wredsum(acc[i] * adr);
        if ((t & 63) == 0) {
            a_src[(n0 + i) * H1 + g] = ps;
            a_dst[(n0 + i) * H1 + g] = pd;
        }
    }
}

// ---------- layer 1 aggregation: ONE WAVE PER NODE, bf16 row gather (uint2/lane) ----------
// 4 nodes per 256-thread block; lane l covers channels 4l..4l+3 (head = l>>4)
__global__ void k_agg1(const int* __restrict__ rowstart, const int* __restrict__ deg,
                       const int2* __restrict__ csr,
                       const float* __restrict__ a_src, const float* __restrict__ a_dst,
                       const float* __restrict__ scal, const unsigned short* __restrict__ h1b,
                       const float* __restrict__ b1, float* __restrict__ out1) {
    __shared__ float4 wlds[4][64];   // [wave][edge-in-chunk] per-head weights, 4 KB
    int wid = threadIdx.x >> 6, lane = threadIdx.x & 63;
    int n = blockIdx.x * 4 + wid;
    int myh = lane >> 4;
    int rs = rowstart[n], cnt = deg[n];
    const float4 adv = ((const float4*)a_dst)[n];
    const float4 wh  = *((const float4*)(scal + 4));
    const uint2* h1v = (const uint2*)h1b;         // row stride = 64 uint2
    const float* wbase = (const float*)(&wlds[wid][0]) + myh;

    float4 M = make_float4(-INFINITY, -INFINITY, -INFINITY, -INFINITY);
    float4 den  = make_float4(0.f, 0.f, 0.f, 0.f);
    float4 acc0 = make_float4(0.f, 0.f, 0.f, 0.f);
    float4 acc1 = make_float4(0.f, 0.f, 0.f, 0.f);

    for (int base = 0; base < cnt; base += 64) {
        int j = base + lane;
        int sj = 0;
        float4 al = make_float4(-INFINITY, -INFINITY, -INFINITY, -INFINITY);
        if (j < cnt) {
            int2 cv = csr[rs + j];
            sj = cv.x;
            float ea = __int_as_float(cv.y);
            float4 as4 = ((const float4*)a_src)[sj];
            al.x = as4.x + adv.x + ea * wh.x;
            al.y = as4.y + adv.y + ea * wh.y;
            al.z = as4.z + adv.z + ea * wh.z;
            al.w = as4.w + adv.w + ea * wh.w;
            al.x = al.x > 0.f ? al.x : NEG_SLOPE * al.x;
            al.y = al.y > 0.f ? al.y : NEG_SLOPE * al.y;
            al.z = al.z > 0.f ? al.z : NEG_SLOPE * al.z;
            al.w = al.w > 0.f ? al.w : NEG_SLOPE * al.w;
        }
        float4 cm = bcast4(wredmax4(al));
        float4 newM = make_float4(fmaxf(M.x, cm.x), fmaxf(M.y, cm.y),
                                  fmaxf(M.z, cm.z), fmaxf(M.w, cm.w));
        float4 sc = make_float4(__expf(M.x - newM.x), __expf(M.y - newM.y),
                                __expf(M.z - newM.z), __expf(M.w - newM.w));
        den.x *= sc.x; den.y *= sc.y; den.z *= sc.z; den.w *= sc.w;
        float scm = comp4(sc, myh);
        acc0.x *= scm; acc0.y *= scm; acc0.z *= scm; acc0.w *= scm;
        acc1.x *= scm; acc1.y *= scm; acc1.z *= scm; acc1.w *= scm;
        M = newM;
        float4 w4 = make_float4(__expf(al.x - M.x), __expf(al.y - M.y),
                                __expf(al.z - M.z), __expf(al.w - M.w));
        den.x += w4.x; den.y += w4.y; den.z += w4.z; den.w += w4.w;
        wlds[wid][lane] = w4;
        int m = min(64, cnt - base);
        int jj = 0;
#pragma unroll 2
        for (; jj + 1 < m; jj += 2) {
            int s0 = __shfl(sj, jj);
            int s1 = __shfl(sj, jj + 1);
            float w0 = wbase[jj * 4];
            float w1 = wbase[jj * 4 + 4];
            uint2 v0 = h1v[(size_t)s0 * 64 + lane];
            uint2 v1 = h1v[(size_t)s1 * 64 + lane];
            acc0.x += __uint_as_float(v0.x << 16)          * w0;
            acc0.y += __uint_as_float(v0.x & 0xffff0000u)  * w0;
            acc0.z += __uint_as_float(v0.y << 16)          * w0;
            acc0.w += __uint_as_float(v0.y & 0xffff0000u)  * w0;
            acc1.x += __uint_as_float(v1.x << 16)          * w1;
            acc1.y += __uint_as_float(v1.x & 0xffff0000u)  * w1;
            acc1.z += __uint_as_float(v1.y << 16)          * w1;
            acc1.w += __uint_as_float(v1.y & 0xffff0000u)  * w1;
        }
        if (jj < m) {
            int s0 = __shfl(sj, jj);
            float w0 = wbase[jj * 4];
            uint2 v0 = h1v[(size_t)s0 * 64 + lane];
            acc0.x += __uint_as_float(v0.x << 16)          * w0;
            acc0.y += __uint_as_float(v0.x & 0xffff0000u)  * w0;
            acc0.z += __uint_as_float(v0.y << 16)          * w0;
            acc0.w += __uint_as_float(v0.y & 0xffff0000u)  * w0;
        }
    }
    float4 dsum = bcast4(wredsum4(den));
    float dt = comp4(dsum, myh) + EPSF;
    float inv = 1.0f / dt;
    float4 b4 = ((const float4*)b1)[lane];
    float4 v;
    v.x = (acc0.x + acc1.x) * inv + b4.x;
    v.y = (acc0.y + acc1.y) * inv + b4.y;
    v.z = (acc0.z + acc1.z) * inv + b4.z;
    v.w = (acc0.w + acc1.w) * inv + b4.w;
    v.x = v.x > 0.f ? v.x : expm1f(v.x);
    v.y = v.y > 0.f ? v.y : expm1f(v.y);
    v.z = v.z > 0.f ? v.z : expm1f(v.z);
    v.w = v.w > 0.f ? v.w : expm1f(v.w);
    ((float4*)(out1 + (size_t)n * HC))[lane] = v;
}

// ---------- layer 2 GEMM: h2(bf16) = out1 @ W2, fused a_src2/a_dst2.  16 nodes per block ----------
__global__ void k_gemm2(const float* __restrict__ out1, const float4* __restrict__ W2r,
                        const float* __restrict__ attsrc, const float* __restrict__ attdst,
                        unsigned short* __restrict__ h2b,
                        float* __restrict__ a_src2, float* __restrict__ a_dst2) {
    __shared__ float rows[16][HC];   // 16 KB
    int n0 = blockIdx.x * 16;
    int t = threadIdx.x;
    {
        float4* r4 = (float4*)rows;
        const float4* og = (const float4*)(out1 + (size_t)n0 * HC);
#pragma unroll
        for (int i = 0; i < 4; ++i) r4[t + i * 256] = og[t + i * 256];
    }
    __syncthreads();
    int c = t & 63, g = t >> 6;   // wave g handles nodes g, g+4, g+8, g+12
    float acc[4] = {0, 0, 0, 0};
#pragma unroll 4
    for (int k4 = 0; k4 < HC / 4; ++k4) {
        float4 wv = W2r[k4 * C + c];
#pragma unroll
        for (int q = 0; q < 4; ++q) {
            float4 rv = *(const float4*)(&rows[g + 4 * q][k4 * 4]);
            acc[q] = fmaf(rv.x, wv.x, fmaf(rv.y, wv.y,
                     fmaf(rv.z, wv.z, fmaf(rv.w, wv.w, acc[q]))));
        }
    }
    float asr = attsrc[c], adr = attdst[c];
#pragma unroll
    for (int q = 0; q < 4; ++q) {
        int n = n0 + g + 4 * q;
        h2b[(size_t)n * C + c] = f2bf(acc[q]);
        float ps = wredsum(acc[q] * asr);
        float pd = wredsum(acc[q] * adr);
        if (c == 0) { a_src2[n] = ps; a_dst2[n] = pd; }
    }
}

// ---------- layer 2 aggregation + classifier head: ONE WAVE PER NODE, bf16 gather ----------
// lane = eg*16 + li : edge-subgroup eg (4 edges in flight), channel-quad li
__global__ void k_agg2(const int* __restrict__ rowstart, const int* __restrict__ deg,
                       const int2* __restrict__ csr,
                       const float* __restrict__ a_src2, const float* __restrict__ a_dst2,
                       const float* __restrict__ scal, const unsigned short* __restrict__ h2b,
                       const float* __restrict__ b2, const float* __restrict__ Wfc,
                       const float* __restrict__ bfc, float* __restrict__ d_out, int N) {
    __shared__ float wlds[4][64];
    int wid = threadIdx.x >> 6, lane = threadIdx.x & 63;
    int n = blockIdx.x * 4 + wid;
    int eg = lane >> 4, li = lane & 15;
    int rs = rowstart[n], cnt = deg[n];
    float adv = a_dst2[n];
    float w2  = scal[2];
    const uint2* h2v = (const uint2*)h2b;   // row stride = 16 uint2 (64 bf16)

    float M = -INFINITY, den = 0.0f;
    float4 acc = make_float4(0.f, 0.f, 0.f, 0.f);

    for (int base = 0; base < cnt; base += 64) {
        int j = base + lane;
        int sj = 0; float al = -INFINITY;
        if (j < cnt) {
            int2 cv = csr[rs + j];
            sj = cv.x;
            al = a_src2[sj] + adv + __int_as_float(cv.y) * w2;
            al = al > 0.0f ? al : NEG_SLOPE * al;
        }
        float cm = wredmax(al); cm = __shfl(cm, 0);
        float newM = fmaxf(M, cm);
        float sc = __expf(M - newM);
        den *= sc;
        acc.x *= sc; acc.y *= sc; acc.z *= sc; acc.w *= sc;
        M = newM;
        float w = __expf(al - M);
        den += w;
        wlds[wid][lane] = w;
        int m = min(64, cnt - base);
#pragma unroll 4
        for (int jj = 0; jj < m; jj += 4) {
            int idx = jj + eg;                     // <= 63 always
            float ww = wlds[wid][idx];             // 0 for padded edges
            int   s  = __shfl(sj, idx);
            uint2 hv = h2v[(size_t)s * 16 + li];
            acc.x += __uint_as_float(hv.x << 16)         * ww;
            acc.y += __uint_as_float(hv.x & 0xffff0000u) * ww;
            acc.z += __uint_as_float(hv.y << 16)         * ww;
            acc.w += __uint_as_float(hv.y & 0xffff0000u) * ww;
        }
    }
    // reduce acc across the 4 edge-subgroups (lanes l, l+16, l+32, l+48)
#pragma unroll
    for (int off = 32; off >= 16; off >>= 1) {
        acc.x += __shfl_down(acc.x, off);
        acc.y += __shfl_down(acc.y, off);
        acc.z += __shfl_down(acc.z, off);
        acc.w += __shfl_down(acc.w, off);
    }
    float dt = wredsum(den); dt = __shfl(dt, 0);
    float inv = 1.0f / (dt + EPSF);
    float4 b4 = ((const float4*)b2)[li];
    float4 v;
    v.x = acc.x * inv + b4.x;
    v.y = acc.y * inv + b4.y;
    v.z = acc.z * inv + b4.z;
    v.w = acc.w * inv + b4.w;
    v.x = v.x > 0.f ? v.x : expm1f(v.x);
    v.y = v.y > 0.f ? v.y : expm1f(v.y);
    v.z = v.z > 0.f ? v.z : expm1f(v.z);
    v.w = v.w > 0.f ? v.w : expm1f(v.w);
    if (lane < 16)
        ((float4*)(d_out + (size_t)2 * N + (size_t)n * C))[li] = v;   // emb
    // classifier: channels 4li..4li+3 on lanes 0..15
    const float4* wfc4 = (const float4*)Wfc;
    float4 A = wfc4[li * 2], B = wfc4[li * 2 + 1];
    float p0 = v.x * A.x + v.y * A.z + v.z * B.x + v.w * B.z;
    float p1 = v.x * A.y + v.y * A.w + v.z * B.y + v.w * B.w;
#pragma unroll
    for (int off = 8; off; off >>= 1) {
        p0 += __shfl_down(p0, off);
        p1 += __shfl_down(p1, off);
    }
    if (lane == 0) {
        p0 += bfc[0]; p1 += bfc[1];
        float mm = fmaxf(p0, p1);
        float lse = mm + logf(__expf(p0 - mm) + __expf(p1 - mm));
        d_out[(size_t)n * 2]     = p0 - lse;
        d_out[(size_t)n * 2 + 1] = p1 - lse;
    }
}

extern "C" void kernel_launch(void* const* d_in, const int* in_sizes, int n_in,
                              void* d_out, int out_size, void* d_ws, size_t ws_size,
                              hipStream_t stream) {
    const float* x     = (const float*)d_in[0];
    const int*   ei    = (const int*)  d_in[1];
    const float* eattr = (const float*)d_in[2];
    const float* W1    = (const float*)d_in[3];
    const float* as1   = (const float*)d_in[4];
    const float* ad1   = (const float*)d_in[5];
    const float* We1   = (const float*)d_in[6];
    const float* ae1   = (const float*)d_in[7];
    const float* b1    = (const float*)d_in[8];
    const float* W2    = (const float*)d_in[9];
    const float* as2   = (const float*)d_in[10];
    const float* ad2   = (const float*)d_in[11];
    const float* We2   = (const float*)d_in[12];
    const float* ae2   = (const float*)d_in[13];
    const float* b2    = (const float*)d_in[14];
    const float* Wfc   = (const float*)d_in[15];
    const float* bfc   = (const float*)d_in[16];

    const int N    = in_sizes[0] / FIN;   // 50000
    const int E    = in_sizes[2];         // 800000
    const int Etot = E + N;

    char* wsb = (char*)d_ws;
    size_t off = 0;
    auto alloc = [&](size_t elems) {
        off = (off + 15) & ~(size_t)15;   // 16B align every buffer
        void* p = wsb + off; off += elems * 4; return p;
    };

    // ---- zero-initialized region (front) ----
    int*   deg    = (int*)  alloc(N);
    int*   cursor = (int*)  alloc(N);
    float* scal   = (float*)alloc(8);
    size_t zero_bytes = (off + 15) & ~(size_t)15;
    // ---- rest ----
    int*   rowstart = (int*)  alloc(N);
    int*   bsums    = (int*)  alloc(256);
    int2*  csr      = (int2*) alloc((size_t)Etot * 2);
    unsigned short* h1b = (unsigned short*)alloc((size_t)N * HC / 2);   // bf16
    unsigned short* h2b = (unsigned short*)alloc((size_t)N * C / 2);    // bf16
    float* out1     = (float*)alloc((size_t)N * HC);
    float* W1r      = (float*)alloc((size_t)FIN * HC);
    float* W2r      = (float*)alloc((size_t)HC * C);
    float* a_src1   = (float*)alloc((size_t)N * H1);
    float* a_dst1   = (float*)alloc((size_t)N * H1);
    float* a_src2   = (float*)alloc(N);
    float* a_dst2   = (float*)alloc(N);

    hipMemsetAsync(d_ws, 0, zero_bytes, stream);

    k_ea_sum<<<(E + 255) / 256, 256, 0, stream>>>(eattr, E, scal);
    k_prep<<<1, 256, 0, stream>>>(We1, ae1, We2, ae2, scal, 1.0f / (float)E);
    k_reord<<<(FIN * HC + 255) / 256, 256, 0, stream>>>(W1, W2, W1r, W2r);

    int ge = (Etot + 255) / 256;
    int nb = (N + 255) / 256;
    k_hist<<<ge, 256, 0, stream>>>(ei, deg, E, Etot);
    k_scan1<<<nb, 256, 0, stream>>>(deg, rowstart, bsums, N);
    k_scan2<<<1, 256, 0, stream>>>(bsums, nb);
    k_scan3<<<nb, 256, 0, stream>>>(rowstart, bsums, N);
    k_scatter<<<ge, 256, 0, stream>>>(ei, eattr, scal, rowstart, cursor, csr, E, Etot);

    k_gemm1<<<N / 16, 256, 0, stream>>>(x, (const float4*)W1r, as1, ad1, h1b, a_src1, a_dst1);
    k_agg1<<<N / 4, 256, 0, stream>>>(rowstart, deg, csr, a_src1, a_dst1, scal, h1b, b1, out1);
    k_gemm2<<<N / 16, 256, 0, stream>>>(out1, (const float4*)W2r, as2, ad2, h2b, a_src2, a_dst2);
    k_agg2<<<N / 4, 256, 0, stream>>>(rowstart, deg, csr, a_src2, a_dst2, scal, h2b,
                                      b2, Wfc, bfc, (float*)d_out, N);
}